// Round 23
// baseline (1147.296 us; speedup 1.0000x reference)
//
#include <hip/hip_runtime.h>
#include <hip/hip_bf16.h>
#include <math.h>

#define N_ROWS 65536
#define ZDIM   256
#define KCODES 1024
#define IDX_OFF  (N_ROWS * ZDIM)        // 16777216
#define LOSS_OFF (IDX_OFF + N_ROWS)     // 16842752
#define ZQ_BLOCKS 2048
#define NC16 16
#define EXCAP (1 << 19)                  // 512K extras (expected ~5-10k)

typedef unsigned int u32;
typedef unsigned short u16;
typedef unsigned char u8;
typedef unsigned long long u64;
typedef __attribute__((ext_vector_type(8))) _Float16 hfrag;  // 8 fp16 (4 VGPR)
typedef __attribute__((ext_vector_type(4))) float ffrag;     // 4 fp32 acc

__device__ __forceinline__ u16 f2h(float x) {
    union { _Float16 h; u16 u; } c; c.h = (_Float16)x; return c.u;   // RN
}

// monotone float<->u32 order-preserving maps
__device__ __forceinline__ u32 mono32(float d) {
    u32 b = __float_as_uint(d);
    return (b & 0x80000000u) ? ~b : (b | 0x80000000u);
}
__device__ __forceinline__ float inv_mono(u32 m) {
    u32 b = (m & 0x80000000u) ? (m ^ 0x80000000u) : ~m;
    return __uint_as_float(b);
}

// ---------------- numpy-pairwise helpers (256 cols) ----------------
__device__ __forceinline__ float np_pw128_sq(const float* __restrict__ p) {
    float r[8];
#pragma unroll
    for (int j = 0; j < 8; ++j) r[j] = __fmul_rn(p[j], p[j]);
    for (int i = 8; i < 128; i += 8) {
#pragma unroll
        for (int j = 0; j < 8; ++j)
            r[j] = __fadd_rn(r[j], __fmul_rn(p[i + j], p[i + j]));
    }
    float a = __fadd_rn(__fadd_rn(r[0], r[1]), __fadd_rn(r[2], r[3]));
    float b = __fadd_rn(__fadd_rn(r[4], r[5]), __fadd_rn(r[6], r[7]));
    return __fadd_rn(a, b);
}

__device__ __forceinline__ float pw128_abs(const float* __restrict__ p) {
    float r[8];
#pragma unroll
    for (int j = 0; j < 8; ++j) r[j] = fabsf(p[j]);
    for (int i = 8; i < 128; i += 8) {
#pragma unroll
        for (int j = 0; j < 8; ++j) r[j] += fabsf(p[i + j]);
    }
    return ((r[0] + r[1]) + (r[2] + r[3])) + ((r[4] + r[5]) + (r[6] + r[7]));
}

// exact OpenBLAS-order dot, float4 loads (same fmaf sequence)
__device__ __forceinline__ float exact_dot(const float* __restrict__ zr,
                                           const float* __restrict__ er) {
    float m = 0.0f;
#pragma unroll 4
    for (int k = 0; k < ZDIM; k += 4) {
        float4 a = *(const float4*)(zr + k);
        float4 b = *(const float4*)(er + k);
        m = fmaf(a.x, b.x, m);
        m = fmaf(a.y, b.y, m);
        m = fmaf(a.z, b.z, m);
        m = fmaf(a.w, b.w, m);
    }
    return m;
}

__global__ void rowsq_kernel(const float* __restrict__ x, float* __restrict__ s, int nrows) {
    int r = blockIdx.x * blockDim.x + threadIdx.x;
    if (r >= nrows) return;
    const float* p = x + (size_t)r * ZDIM;
    s[r] = __fadd_rn(np_pw128_sq(p), np_pw128_sq(p + 128));
}

// sz (np-exact) + per-row rigorous eps for the 1-pass fp16 bound
__global__ void rowsq_eps_kernel(const float* __restrict__ x, float* __restrict__ s,
                                 float* __restrict__ epsr) {
    int r = blockIdx.x * blockDim.x + threadIdx.x;
    const float* p = x + (size_t)r * ZDIM;
    s[r] = __fadd_rn(np_pw128_sq(p), np_pw128_sq(p + 128));
    float S1 = pw128_abs(p) + pw128_abs(p + 128);
    epsr[r] = fmaf(S1, 1.1e-6f, 6e-5f);
}

// ---------------- z -> fp16 (RN), row-major, into d_out z_q region ----------
__global__ __launch_bounds__(256) void split_z_kernel(
    const float* __restrict__ z, u16* __restrict__ zh) {
    int t = blockIdx.x * 256 + threadIdx.x;
    int i = t * 8;
    float4 a = *(const float4*)(z + i);
    float4 b = *(const float4*)(z + i + 4);
    uint4 w;
    w.x = ((u32)f2h(a.y) << 16) | f2h(a.x);
    w.y = ((u32)f2h(a.w) << 16) | f2h(a.z);
    w.z = ((u32)f2h(b.y) << 16) | f2h(b.x);
    w.w = ((u32)f2h(b.w) << 16) | f2h(b.z);
    *(uint4*)(zh + i) = w;
}

// ---------------- e -> fp16 scaled x64, FRAGMENT-MAJOR layout ----------------
__global__ __launch_bounds__(256) void split_e_kernel(
    const float* __restrict__ e, u16* __restrict__ ehf) {
    int t = blockIdx.x * 256 + threadIdx.x;      // 65536 threads
    int c = t >> 6, kq = t & 63;                 // dims kq*4 .. +3
    float4 v = *(const float4*)(e + (size_t)c * ZDIM + kq * 4);
    ushort4 h;
    h.x = f2h(v.x * 64.0f); h.y = f2h(v.y * 64.0f);
    h.z = f2h(v.z * 64.0f); h.w = f2h(v.w * 64.0f);
    int c16 = c >> 6, ct = (c >> 4) & 3, lr = c & 15;
    int kc = kq >> 3, lk = (kq >> 1) & 3;
    int lane = lk * 16 + lr;
    size_t base = ((size_t)((c16 * 8 + kc) * 4 + ct) * 64 + lane) * 8 + ((kq * 4) & 7);
    *(ushort4*)(ehf + base) = h;
}

// ---------------- LDS-shared fp16 MFMA, per-chunk (rmin,argcode) ------------
// v23: per-c16 butterfly carries (rmin, argcode) -> dense transposed cqc u64
// store. Extras (window candidates beyond chunk argmin) -> small global list +
// exflag[row]=1 (idempotent, OR across the two cp blocks). Resolution moved
// OUT of this kernel (v22's bug: each cp block saw only 8/16 chunks but wrote
// final indices).
__global__ __launch_bounds__(256) void mfma_argmin_kernel(
    const u16* __restrict__ zh, const u16* __restrict__ ehf,
    const float* __restrict__ sz, const float* __restrict__ se,
    const float* __restrict__ epsr, u64* __restrict__ cqc,
    int* __restrict__ ex_row, u64* __restrict__ ex_key, int* __restrict__ ex_cnt,
    u8* __restrict__ exflag) {
    __shared__ __align__(16) char ehL[2][16384];      // 32 KB (double buffer)
    __shared__ float sse[KCODES];                     // 4 KB
    const int tid = threadIdx.x;
    const int lane = tid & 63;
    const int lr = lane & 15, lk = lane >> 4;
    const int rp = blockIdx.x >> 1, cp = blockIdx.x & 1;
    const int wr0 = rp * 128 + (tid >> 6) * 32;

    *(float4*)(sse + tid * 4) = *(const float4*)(se + tid * 4);

    float szv[2][4], epsv[2][4];
#pragma unroll
    for (int rt = 0; rt < 2; ++rt)
#pragma unroll
        for (int j = 0; j < 4; ++j) {
            szv[rt][j]  = sz[wr0 + rt * 16 + lk * 4 + j];
            epsv[rt][j] = epsr[wr0 + rt * 16 + lk * 4 + j];
        }

    hfrag A[2][8];
#pragma unroll
    for (int rt = 0; rt < 2; ++rt)
#pragma unroll
        for (int kc = 0; kc < 8; ++kc)
            A[rt][kc] = *(const hfrag*)(zh + (size_t)(wr0 + rt * 16 + lr) * ZDIM + kc * 32 + lk * 8);

    const char* ehpb = (const char*)ehf + (size_t)cp * 8 * 32768;  // this cp half

    // prologue: stage segment 0 into buf0
    {
        const char* src = ehpb;
        uint4 s0 = *(const uint4*)(src + tid * 16);
        uint4 s1 = *(const uint4*)(src + 4096 + tid * 16);
        uint4 s2 = *(const uint4*)(src + 8192 + tid * 16);
        uint4 s3 = *(const uint4*)(src + 12288 + tid * 16);
        *(uint4*)(&ehL[0][tid * 16])         = s0;
        *(uint4*)(&ehL[0][4096 + tid * 16])  = s1;
        *(uint4*)(&ehL[0][8192 + tid * 16])  = s2;
        *(uint4*)(&ehL[0][12288 + tid * 16]) = s3;
    }
    __syncthreads();   // seg0 staged; also covers sse init

    ffrag acc[2][4];
    int hEx[2][4];
#pragma unroll
    for (int rt = 0; rt < 2; ++rt)
#pragma unroll
        for (int j = 0; j < 4; ++j) hEx[rt][j] = 0;

#pragma unroll 1
    for (int cc = 0; cc < 8; ++cc) {
        const int c16 = cp * 8 + cc;

        // ===== phase h=0: compute seg 2cc (buf0, kc 0..3); stage 2cc+1 -> buf1
        {
#pragma unroll
            for (int rt = 0; rt < 2; ++rt)
#pragma unroll
                for (int ct = 0; ct < 4; ++ct) acc[rt][ct] = (ffrag)(0.0f);
            const char* src = ehpb + (size_t)(2 * cc + 1) * 16384;
            uint4 s0 = *(const uint4*)(src + tid * 16);
            uint4 s1 = *(const uint4*)(src + 4096 + tid * 16);
            uint4 s2 = *(const uint4*)(src + 8192 + tid * 16);
            uint4 s3 = *(const uint4*)(src + 12288 + tid * 16);
            const char* buf = ehL[0];
#pragma unroll
            for (int kcl = 0; kcl < 4; ++kcl) {
#pragma unroll
                for (int ct = 0; ct < 4; ++ct) {
                    hfrag bh = *(const hfrag*)(buf + (size_t)(kcl * 4 + ct) * 1024 + (size_t)lane * 16);
                    acc[0][ct] = __builtin_amdgcn_mfma_f32_16x16x32_f16(A[0][kcl], bh, acc[0][ct], 0, 0, 0);
                    acc[1][ct] = __builtin_amdgcn_mfma_f32_16x16x32_f16(A[1][kcl], bh, acc[1][ct], 0, 0, 0);
                }
            }
            char* dst = ehL[1];
            *(uint4*)(dst + tid * 16)         = s0;
            *(uint4*)(dst + 4096 + tid * 16)  = s1;
            *(uint4*)(dst + 8192 + tid * 16)  = s2;
            *(uint4*)(dst + 12288 + tid * 16) = s3;
            __syncthreads();
        }

        // ===== phase h=1: compute seg 2cc+1 (buf1, kc 4..7); stage 2cc+2 -> buf0
        {
            uint4 s0, s1, s2, s3;
            const bool more = (cc < 7);
            if (more) {
                const char* src = ehpb + (size_t)(2 * cc + 2) * 16384;
                s0 = *(const uint4*)(src + tid * 16);
                s1 = *(const uint4*)(src + 4096 + tid * 16);
                s2 = *(const uint4*)(src + 8192 + tid * 16);
                s3 = *(const uint4*)(src + 12288 + tid * 16);
            }
            const char* buf = ehL[1];
#pragma unroll
            for (int kcl = 0; kcl < 4; ++kcl) {
#pragma unroll
                for (int ct = 0; ct < 4; ++ct) {
                    hfrag bh = *(const hfrag*)(buf + (size_t)(kcl * 4 + ct) * 1024 + (size_t)lane * 16);
                    acc[0][ct] = __builtin_amdgcn_mfma_f32_16x16x32_f16(A[0][4 + kcl], bh, acc[0][ct], 0, 0, 0);
                    acc[1][ct] = __builtin_amdgcn_mfma_f32_16x16x32_f16(A[1][4 + kcl], bh, acc[1][ct], 0, 0, 0);
                }
            }
            if (more) {
                char* dst = ehL[0];
                *(uint4*)(dst + tid * 16)         = s0;
                *(uint4*)(dst + 4096 + tid * 16)  = s1;
                *(uint4*)(dst + 8192 + tid * 16)  = s2;
                *(uint4*)(dst + 12288 + tid * 16) = s3;
            }

            // ---- epilogue for c16 ----
            float lm[2][4]; int lcd[2][4];
#pragma unroll
            for (int rt = 0; rt < 2; ++rt)
#pragma unroll
                for (int j = 0; j < 4; ++j) { lm[rt][j] = __builtin_inff(); lcd[rt][j] = 0; }
#pragma unroll
            for (int rt = 0; rt < 2; ++rt)
#pragma unroll
                for (int ct = 0; ct < 4; ++ct) {
                    float sec = sse[c16 * 64 + ct * 16 + lr];
#pragma unroll
                    for (int j = 0; j < 4; ++j) {
                        float dd = __fsub_rn(__fadd_rn(szv[rt][j], sec), 0.03125f * acc[rt][ct][j]);
                        if (dd < lm[rt][j]) { lm[rt][j] = dd; lcd[rt][j] = c16 * 64 + ct * 16 + lr; }
                    }
                }
            // butterfly: (rmin, argcode) over the row's 16 lanes, lexicographic
#pragma unroll
            for (int m = 1; m < 16; m <<= 1)
#pragma unroll
                for (int rt = 0; rt < 2; ++rt)
#pragma unroll
                    for (int j = 0; j < 4; ++j) {
                        float om = __shfl_xor(lm[rt][j], m, 64);
                        int   oc = __shfl_xor(lcd[rt][j], m, 64);
                        if (om < lm[rt][j] || (om == lm[rt][j] && oc < lcd[rt][j])) {
                            lm[rt][j] = om; lcd[rt][j] = oc;
                        }
                    }
            // extras emission (window beyond chunk argmin)
#pragma unroll
            for (int rt = 0; rt < 2; ++rt)
#pragma unroll
                for (int j = 0; j < 4; ++j) {
                    const float thr = fmaf(2.0f, epsv[rt][j], lm[rt][j]);
#pragma unroll
                    for (int ct = 0; ct < 4; ++ct) {
                        float dd = __fsub_rn(__fadd_rn(szv[rt][j], sse[c16 * 64 + ct * 16 + lr]),
                                             0.03125f * acc[rt][ct][j]);
                        const int code = c16 * 64 + ct * 16 + lr;
                        const bool emit = (dd <= thr) && (code != lcd[rt][j]);
                        u64 bal = __ballot(emit);
                        u32 grp = (u32)(bal >> (lk * 16)) & 0xFFFFu;
                        hEx[rt][j] |= (grp != 0);
                        if (emit) {
                            int pos = atomicAdd(ex_cnt, 1);
                            if (pos < EXCAP) {
                                ex_row[pos] = wr0 + rt * 16 + lk * 4 + j;
                                ex_key[pos] = ((u64)mono32(dd) << 32) | (u32)code;
                            }
                        }
                    }
                }
            // cqc store (transposed, dense)
            if (lr == 0) {
#pragma unroll
                for (int rt = 0; rt < 2; ++rt)
#pragma unroll
                    for (int j = 0; j < 4; ++j)
                        cqc[(size_t)c16 * N_ROWS + wr0 + rt * 16 + lk * 4 + j] =
                            ((u64)mono32(lm[rt][j]) << 32) | (u32)lcd[rt][j];
            }
            __syncthreads();
        }
    }
    // exflag (OR across cp blocks via pre-zeroed buffer; write only 1s)
    if (lr == 0) {
#pragma unroll
        for (int rt = 0; rt < 2; ++rt)
#pragma unroll
            for (int j = 0; j < 4; ++j)
                if (hEx[rt][j]) exflag[wr0 + rt * 16 + lk * 4 + j] = 1;
    }
}

// ---------------- resolve: fastpath + ambiguous worklist (all 16 chunks) ----
__global__ __launch_bounds__(256) void resolve_kernel(
    const u8* __restrict__ exflag, const float* __restrict__ epsr,
    const u64* __restrict__ cqc, int* __restrict__ out_idx,
    float* __restrict__ out_idx_f, int* __restrict__ wl, int* __restrict__ wl_cnt) {
    const int row = blockIdx.x * 256 + threadIdx.x;
    const int lane = threadIdx.x & 63;
    u64 best = ~0ull;
    u32 d2m = 0xFFFFFFFFu;
#pragma unroll
    for (int i = 0; i < NC16; ++i) {
        u64 k = cqc[(size_t)i * N_ROWS + row];
        if (k < best) { d2m = min(d2m, (u32)(best >> 32)); best = k; }
        else          { d2m = min(d2m, (u32)(k >> 32)); }
    }
    const float d1 = inv_mono((u32)(best >> 32));
    const float thr = fmaf(2.0f, epsr[row], d1);
    const bool amb = exflag[row] || (inv_mono(d2m) <= thr);
    if (!amb) {
        const int c = (int)(u32)best;
        out_idx[row] = c;
        out_idx_f[row] = (float)c;
    }
    u64 mask = __ballot(amb);
    int cw = __popcll(mask);
    int base = 0;
    if (lane == 0 && cw) base = atomicAdd(wl_cnt, cw);
    base = __shfl(base, 0, 64);
    if (amb) {
        int rank = __popcll(mask & ((1ull << lane) - 1ull));
        wl[base + rank] = row;
    }
}

// ---------------- rescore A: chunk-min candidates of ambiguous rows ---------
__global__ __launch_bounds__(256) void rescore_chunk_kernel(
    const float* __restrict__ z, const float* __restrict__ e,
    const float* __restrict__ sz, const float* __restrict__ se,
    const float* __restrict__ epsr, const u64* __restrict__ cqc,
    const int* __restrict__ wl, const int* __restrict__ wl_cnt,
    u64* __restrict__ rkey) {
    const int total = wl_cnt[0] * NC16;
    for (int t = blockIdx.x * 256 + threadIdx.x; t < total; t += gridDim.x * 256) {
        const int wi = t >> 4, c16 = t & 15;
        const int row = wl[wi];
        u32 gm = 0xFFFFFFFFu;
        u64 myk = 0;
#pragma unroll
        for (int i = 0; i < NC16; ++i) {
            u64 k = cqc[(size_t)i * N_ROWS + row];
            gm = min(gm, (u32)(k >> 32));
            if (i == c16) myk = k;
        }
        const float thr = fmaf(2.0f, epsr[row], inv_mono(gm));
        if ((u32)(myk >> 32) <= mono32(thr)) {
            const int c = (int)(u32)myk;
            float m = exact_dot(z + (size_t)row * ZDIM, e + (size_t)c * ZDIM);
            float d = __fsub_rn(__fadd_rn(sz[row], se[c]), 2.0f * m);
            atomicMin(&rkey[row], ((u64)mono32(d) << 32) | (u32)c);
        }
    }
}

// ---------------- rescore B: extras list ----------------
__global__ __launch_bounds__(256) void rescore_extras_kernel(
    const float* __restrict__ z, const float* __restrict__ e,
    const float* __restrict__ sz, const float* __restrict__ se,
    const float* __restrict__ epsr, const u64* __restrict__ cqc,
    const int* __restrict__ ex_row, const u64* __restrict__ ex_key,
    const int* __restrict__ ex_cnt, u64* __restrict__ rkey) {
    const int n = min(ex_cnt[0], EXCAP);
    for (int i = blockIdx.x * 256 + threadIdx.x; i < n; i += gridDim.x * 256) {
        const int row = ex_row[i];
        const u64 key = ex_key[i];
        u32 gm = 0xFFFFFFFFu;
#pragma unroll
        for (int k = 0; k < NC16; ++k)
            gm = min(gm, (u32)(cqc[(size_t)k * N_ROWS + row] >> 32));
        const float thr = fmaf(2.0f, epsr[row], inv_mono(gm));
        if ((u32)(key >> 32) <= mono32(thr)) {
            const int c = (int)(u32)key;
            float m = exact_dot(z + (size_t)row * ZDIM, e + (size_t)c * ZDIM);
            float d = __fsub_rn(__fadd_rn(sz[row], se[c]), 2.0f * m);
            atomicMin(&rkey[row], ((u64)mono32(d) << 32) | (u32)c);
        }
    }
}

// ---------------- rescore C: unpack ambiguous winners ----------------
__global__ __launch_bounds__(256) void rescore_final_kernel(
    const int* __restrict__ wl, const int* __restrict__ wl_cnt,
    const u64* __restrict__ rkey, int* __restrict__ out_idx,
    float* __restrict__ out_idx_f) {
    const int n = wl_cnt[0];
    for (int i = blockIdx.x * 256 + threadIdx.x; i < n; i += gridDim.x * 256) {
        const int row = wl[i];
        const int c = (int)(u32)rkey[row];
        out_idx[row] = c;
        out_idx_f[row] = (float)c;
    }
}

// ---------------- z_q_st + loss partial (no atomics) ----------------
__global__ __launch_bounds__(256) void zq_loss_kernel(
    const float* __restrict__ z, const float* __restrict__ e,
    const int* __restrict__ idx, float* __restrict__ out,
    double* __restrict__ partial) {
    const int tid = threadIdx.x;
    const int rl  = tid >> 6;
    const int ln  = tid & 63;
    const int row0 = blockIdx.x * 32;

    float acc = 0.0f;
#pragma unroll
    for (int it = 0; it < 8; ++it) {
        int row = row0 + it * 4 + rl;
        int code = idx[row];
        const float4 vz = *(const float4*)(z + (size_t)row  * ZDIM + ln * 4);
        const float4 vq = *(const float4*)(e + (size_t)code * ZDIM + ln * 4);
        float4 o;
        float dx = __fsub_rn(vq.x, vz.x);
        float dy = __fsub_rn(vq.y, vz.y);
        float dz_ = __fsub_rn(vq.z, vz.z);
        float dw = __fsub_rn(vq.w, vz.w);
        o.x = __fadd_rn(vz.x, dx);
        o.y = __fadd_rn(vz.y, dy);
        o.z = __fadd_rn(vz.z, dz_);
        o.w = __fadd_rn(vz.w, dw);
        *(float4*)(out + (size_t)row * ZDIM + ln * 4) = o;
        acc = __fadd_rn(acc, __fmul_rn(dx, dx));
        acc = __fadd_rn(acc, __fmul_rn(dy, dy));
        acc = __fadd_rn(acc, __fmul_rn(dz_, dz_));
        acc = __fadd_rn(acc, __fmul_rn(dw, dw));
    }

    __shared__ double red[256];
    red[tid] = (double)acc;
    __syncthreads();
#pragma unroll
    for (int s = 128; s > 0; s >>= 1) {
        if (tid < s) red[tid] += red[tid + s];
        __syncthreads();
    }
    if (tid == 0) partial[blockIdx.x] = red[0];
}

__global__ __launch_bounds__(256) void loss_final_kernel(
    const double* __restrict__ partial, float* __restrict__ out_loss) {
    const int tid = threadIdx.x;
    double s = 0.0;
    for (int i = tid; i < ZQ_BLOCKS; i += 256) s += partial[i];
    __shared__ double red[256];
    red[tid] = s;
    __syncthreads();
#pragma unroll
    for (int st = 128; st > 0; st >>= 1) {
        if (tid < st) red[tid] += red[tid + st];
        __syncthreads();
    }
    if (tid == 0) {
        double M = red[0] / 16777216.0;
        float m32 = (float)M;
        out_loss[0] = __fadd_rn(m32, __fmul_rn(0.25f, m32));
    }
}

extern "C" void kernel_launch(void* const* d_in, const int* in_sizes, int n_in,
                              void* d_out, int out_size, void* d_ws, size_t ws_size,
                              hipStream_t stream) {
    const float* z = (const float*)d_in[0];
    const float* e = (const float*)d_in[1];
    float* out = (float*)d_out;
    char* ws = (char*)d_ws;

    size_t off = 0;
    double* partial = (double*)(ws + off); off += ZQ_BLOCKS * sizeof(double);   // 16 KB
    float*  sz      = (float*) (ws + off); off += (size_t)N_ROWS * 4;           // 256 KB
    float*  epsr    = (float*) (ws + off); off += (size_t)N_ROWS * 4;           // 256 KB
    float*  se      = (float*) (ws + off); off += (size_t)KCODES * 4;           // 4 KB
    int*    idx     = (int*)   (ws + off); off += (size_t)N_ROWS * 4;           // 256 KB
    u16*    ehf     = (u16*)   (ws + off); off += (size_t)KCODES * ZDIM * 2;    // 512 KB
    u64*    cqc     = (u64*)   (ws + off); off += (size_t)NC16 * N_ROWS * 8;    // 8 MB
    int*    wl      = (int*)   (ws + off); off += (size_t)N_ROWS * 4;           // 256 KB
    int*    ex_row  = (int*)   (ws + off); off += (size_t)EXCAP * 4;            // 2 MB
    u64*    ex_key  = (u64*)   (ws + off); off += (size_t)EXCAP * 8;            // 4 MB
    u64*    rkey    = (u64*)   (ws + off); off += (size_t)N_ROWS * 8;           // 512 KB
    u8*     exflag  = (u8*)    (ws + off); off += (size_t)N_ROWS;               // 64 KB
    int*    cnts    = (int*)   (ws + off); off += 32;                           // wl_cnt, ex_cnt
    int* wl_cnt = cnts;
    int* ex_cnt = cnts + 1;

    u16* zh = (u16*)out;   // fp16 z in d_out z_q region; zq_loss overwrites later

    hipMemsetAsync(cnts, 0, 32, stream);
    hipMemsetAsync(exflag, 0, (size_t)N_ROWS, stream);
    hipMemsetAsync(rkey, 0xFF, (size_t)N_ROWS * 8, stream);
    split_z_kernel<<<8192, 256, 0, stream>>>(z, zh);
    split_e_kernel<<<256, 256, 0, stream>>>(e, ehf);
    rowsq_eps_kernel<<<N_ROWS / 256, 256, 0, stream>>>(z, sz, epsr);
    rowsq_kernel<<<KCODES / 256, 256, 0, stream>>>(e, se, KCODES);
    mfma_argmin_kernel<<<1024, 256, 0, stream>>>(zh, ehf, sz, se, epsr, cqc,
                                                 ex_row, ex_key, ex_cnt, exflag);
    resolve_kernel<<<N_ROWS / 256, 256, 0, stream>>>(exflag, epsr, cqc,
                                                     idx, out + IDX_OFF, wl, wl_cnt);
    rescore_chunk_kernel<<<256, 256, 0, stream>>>(z, e, sz, se, epsr, cqc, wl, wl_cnt, rkey);
    rescore_extras_kernel<<<256, 256, 0, stream>>>(z, e, sz, se, epsr, cqc,
                                                   ex_row, ex_key, ex_cnt, rkey);
    rescore_final_kernel<<<256, 256, 0, stream>>>(wl, wl_cnt, rkey, idx, out + IDX_OFF);
    zq_loss_kernel<<<ZQ_BLOCKS, 256, 0, stream>>>(z, e, idx, out, partial);
    loss_final_kernel<<<1, 256, 0, stream>>>(partial, out + LOSS_OFF);
}

// Round 24
// 318.919 us; speedup vs baseline: 3.5975x; 3.5975x over previous
//
#include <hip/hip_runtime.h>
#include <hip/hip_bf16.h>
#include <math.h>

#define N_ROWS 65536
#define ZDIM   256
#define KCODES 1024
#define IDX_OFF  (N_ROWS * ZDIM)        // 16777216
#define LOSS_OFF (IDX_OFF + N_ROWS)     // 16842752
#define ZQ_BLOCKS 2048
#define NC16 16

typedef unsigned int u32;
typedef unsigned short u16;
typedef unsigned long long u64;
typedef __attribute__((ext_vector_type(8))) _Float16 hfrag;  // 8 fp16 (4 VGPR)
typedef __attribute__((ext_vector_type(4))) float ffrag;     // 4 fp32 acc

__device__ __forceinline__ u16 f2h(float x) {
    union { _Float16 h; u16 u; } c; c.h = (_Float16)x; return c.u;   // RN
}

// monotone float<->u32 order-preserving maps
__device__ __forceinline__ u32 mono32(float d) {
    u32 b = __float_as_uint(d);
    return (b & 0x80000000u) ? ~b : (b | 0x80000000u);
}
__device__ __forceinline__ float inv_mono(u32 m) {
    u32 b = (m & 0x80000000u) ? (m ^ 0x80000000u) : ~m;
    return __uint_as_float(b);
}

// ---------------- numpy-pairwise helpers (256 cols) ----------------
__device__ __forceinline__ float np_pw128_sq(const float* __restrict__ p) {
    float r[8];
#pragma unroll
    for (int j = 0; j < 8; ++j) r[j] = __fmul_rn(p[j], p[j]);
    for (int i = 8; i < 128; i += 8) {
#pragma unroll
        for (int j = 0; j < 8; ++j)
            r[j] = __fadd_rn(r[j], __fmul_rn(p[i + j], p[i + j]));
    }
    float a = __fadd_rn(__fadd_rn(r[0], r[1]), __fadd_rn(r[2], r[3]));
    float b = __fadd_rn(__fadd_rn(r[4], r[5]), __fadd_rn(r[6], r[7]));
    return __fadd_rn(a, b);
}

__device__ __forceinline__ float pw128_abs(const float* __restrict__ p) {
    float r[8];
#pragma unroll
    for (int j = 0; j < 8; ++j) r[j] = fabsf(p[j]);
    for (int i = 8; i < 128; i += 8) {
#pragma unroll
        for (int j = 0; j < 8; ++j) r[j] += fabsf(p[i + j]);
    }
    return ((r[0] + r[1]) + (r[2] + r[3])) + ((r[4] + r[5]) + (r[6] + r[7]));
}

// exact OpenBLAS-order dot, float4 loads (same fmaf sequence)
__device__ __forceinline__ float exact_dot(const float* __restrict__ zr,
                                           const float* __restrict__ er) {
    float m = 0.0f;
#pragma unroll 4
    for (int k = 0; k < ZDIM; k += 4) {
        float4 a = *(const float4*)(zr + k);
        float4 b = *(const float4*)(er + k);
        m = fmaf(a.x, b.x, m);
        m = fmaf(a.y, b.y, m);
        m = fmaf(a.z, b.z, m);
        m = fmaf(a.w, b.w, m);
    }
    return m;
}

__global__ void rowsq_kernel(const float* __restrict__ x, float* __restrict__ s, int nrows) {
    int r = blockIdx.x * blockDim.x + threadIdx.x;
    if (r >= nrows) return;
    const float* p = x + (size_t)r * ZDIM;
    s[r] = __fadd_rn(np_pw128_sq(p), np_pw128_sq(p + 128));
}

// sz (np-exact) + per-row rigorous eps for the 1-pass fp16 bound
__global__ void rowsq_eps_kernel(const float* __restrict__ x, float* __restrict__ s,
                                 float* __restrict__ epsr) {
    int r = blockIdx.x * blockDim.x + threadIdx.x;
    const float* p = x + (size_t)r * ZDIM;
    s[r] = __fadd_rn(np_pw128_sq(p), np_pw128_sq(p + 128));
    float S1 = pw128_abs(p) + pw128_abs(p + 128);
    epsr[r] = fmaf(S1, 1.1e-6f, 6e-5f);
}

// ---------------- z -> fp16 (RN), row-major, into d_out z_q region ----------
__global__ __launch_bounds__(256) void split_z_kernel(
    const float* __restrict__ z, u16* __restrict__ zh) {
    int t = blockIdx.x * 256 + threadIdx.x;
    int i = t * 8;
    float4 a = *(const float4*)(z + i);
    float4 b = *(const float4*)(z + i + 4);
    uint4 w;
    w.x = ((u32)f2h(a.y) << 16) | f2h(a.x);
    w.y = ((u32)f2h(a.w) << 16) | f2h(a.z);
    w.z = ((u32)f2h(b.y) << 16) | f2h(b.x);
    w.w = ((u32)f2h(b.w) << 16) | f2h(b.z);
    *(uint4*)(zh + i) = w;
}

// ---------------- e -> fp16 scaled x64, FRAGMENT-MAJOR layout ----------------
__global__ __launch_bounds__(256) void split_e_kernel(
    const float* __restrict__ e, u16* __restrict__ ehf) {
    int t = blockIdx.x * 256 + threadIdx.x;      // 65536 threads
    int c = t >> 6, kq = t & 63;                 // dims kq*4 .. +3
    float4 v = *(const float4*)(e + (size_t)c * ZDIM + kq * 4);
    ushort4 h;
    h.x = f2h(v.x * 64.0f); h.y = f2h(v.y * 64.0f);
    h.z = f2h(v.z * 64.0f); h.w = f2h(v.w * 64.0f);
    int c16 = c >> 6, ct = (c >> 4) & 3, lr = c & 15;
    int kc = kq >> 3, lk = (kq >> 1) & 3;
    int lane = lk * 16 + lr;
    size_t base = ((size_t)((c16 * 8 + kc) * 4 + ct) * 64 + lane) * 8 + ((kq * 4) & 7);
    *(ushort4*)(ehf + base) = h;
}

// ---------------- LDS-shared fp16 MFMA, per-chunk TOP-2 (no atomics) --------
// v24: epilogue computes per-chunk top-2 (d~, code) via lexicographic
// butterfly; stores cqc1/cqc2 dense transposed u64. NO emission, NO atomics
// (r23's single ex_cnt counter serialized ~1M blocking round-trips).
__global__ __launch_bounds__(256) void mfma_argmin_kernel(
    const u16* __restrict__ zh, const u16* __restrict__ ehf,
    const float* __restrict__ sz, const float* __restrict__ se,
    u64* __restrict__ cqc1, u64* __restrict__ cqc2) {
    __shared__ __align__(16) char ehL[2][16384];      // 32 KB (double buffer)
    __shared__ float sse[KCODES];                     // 4 KB
    const int tid = threadIdx.x;
    const int lane = tid & 63;
    const int lr = lane & 15, lk = lane >> 4;
    const int rp = blockIdx.x >> 1, cp = blockIdx.x & 1;
    const int wr0 = rp * 128 + (tid >> 6) * 32;

    *(float4*)(sse + tid * 4) = *(const float4*)(se + tid * 4);

    float szv[2][4];
#pragma unroll
    for (int rt = 0; rt < 2; ++rt)
#pragma unroll
        for (int j = 0; j < 4; ++j)
            szv[rt][j] = sz[wr0 + rt * 16 + lk * 4 + j];

    hfrag A[2][8];
#pragma unroll
    for (int rt = 0; rt < 2; ++rt)
#pragma unroll
        for (int kc = 0; kc < 8; ++kc)
            A[rt][kc] = *(const hfrag*)(zh + (size_t)(wr0 + rt * 16 + lr) * ZDIM + kc * 32 + lk * 8);

    const char* ehpb = (const char*)ehf + (size_t)cp * 8 * 32768;  // this cp half

    // prologue: stage segment 0 into buf0
    {
        const char* src = ehpb;
        uint4 s0 = *(const uint4*)(src + tid * 16);
        uint4 s1 = *(const uint4*)(src + 4096 + tid * 16);
        uint4 s2 = *(const uint4*)(src + 8192 + tid * 16);
        uint4 s3 = *(const uint4*)(src + 12288 + tid * 16);
        *(uint4*)(&ehL[0][tid * 16])         = s0;
        *(uint4*)(&ehL[0][4096 + tid * 16])  = s1;
        *(uint4*)(&ehL[0][8192 + tid * 16])  = s2;
        *(uint4*)(&ehL[0][12288 + tid * 16]) = s3;
    }
    __syncthreads();   // seg0 staged; also covers sse init

    ffrag acc[2][4];

#pragma unroll 1
    for (int cc = 0; cc < 8; ++cc) {
        const int c16 = cp * 8 + cc;

        // ===== phase h=0: compute seg 2cc (buf0, kc 0..3); stage 2cc+1 -> buf1
        {
#pragma unroll
            for (int rt = 0; rt < 2; ++rt)
#pragma unroll
                for (int ct = 0; ct < 4; ++ct) acc[rt][ct] = (ffrag)(0.0f);
            const char* src = ehpb + (size_t)(2 * cc + 1) * 16384;
            uint4 s0 = *(const uint4*)(src + tid * 16);
            uint4 s1 = *(const uint4*)(src + 4096 + tid * 16);
            uint4 s2 = *(const uint4*)(src + 8192 + tid * 16);
            uint4 s3 = *(const uint4*)(src + 12288 + tid * 16);
            const char* buf = ehL[0];
#pragma unroll
            for (int kcl = 0; kcl < 4; ++kcl) {
#pragma unroll
                for (int ct = 0; ct < 4; ++ct) {
                    hfrag bh = *(const hfrag*)(buf + (size_t)(kcl * 4 + ct) * 1024 + (size_t)lane * 16);
                    acc[0][ct] = __builtin_amdgcn_mfma_f32_16x16x32_f16(A[0][kcl], bh, acc[0][ct], 0, 0, 0);
                    acc[1][ct] = __builtin_amdgcn_mfma_f32_16x16x32_f16(A[1][kcl], bh, acc[1][ct], 0, 0, 0);
                }
            }
            char* dst = ehL[1];
            *(uint4*)(dst + tid * 16)         = s0;
            *(uint4*)(dst + 4096 + tid * 16)  = s1;
            *(uint4*)(dst + 8192 + tid * 16)  = s2;
            *(uint4*)(dst + 12288 + tid * 16) = s3;
            __syncthreads();
        }

        // ===== phase h=1: compute seg 2cc+1 (buf1, kc 4..7); stage 2cc+2 -> buf0
        {
            uint4 s0, s1, s2, s3;
            const bool more = (cc < 7);
            if (more) {
                const char* src = ehpb + (size_t)(2 * cc + 2) * 16384;
                s0 = *(const uint4*)(src + tid * 16);
                s1 = *(const uint4*)(src + 4096 + tid * 16);
                s2 = *(const uint4*)(src + 8192 + tid * 16);
                s3 = *(const uint4*)(src + 12288 + tid * 16);
            }
            const char* buf = ehL[1];
#pragma unroll
            for (int kcl = 0; kcl < 4; ++kcl) {
#pragma unroll
                for (int ct = 0; ct < 4; ++ct) {
                    hfrag bh = *(const hfrag*)(buf + (size_t)(kcl * 4 + ct) * 1024 + (size_t)lane * 16);
                    acc[0][ct] = __builtin_amdgcn_mfma_f32_16x16x32_f16(A[0][4 + kcl], bh, acc[0][ct], 0, 0, 0);
                    acc[1][ct] = __builtin_amdgcn_mfma_f32_16x16x32_f16(A[1][4 + kcl], bh, acc[1][ct], 0, 0, 0);
                }
            }
            if (more) {
                char* dst = ehL[0];
                *(uint4*)(dst + tid * 16)         = s0;
                *(uint4*)(dst + 4096 + tid * 16)  = s1;
                *(uint4*)(dst + 8192 + tid * 16)  = s2;
                *(uint4*)(dst + 12288 + tid * 16) = s3;
            }

            // ---- epilogue for c16: per-lane top-2 over ct, butterfly top-2 ----
            float d1v[2][4], d2v[2][4];
            int   q1v[2][4], q2v[2][4];
#pragma unroll
            for (int rt = 0; rt < 2; ++rt)
#pragma unroll
                for (int j = 0; j < 4; ++j) {
                    d1v[rt][j] = __builtin_inff(); d2v[rt][j] = __builtin_inff();
                    q1v[rt][j] = 0; q2v[rt][j] = 0;
                }
#pragma unroll
            for (int rt = 0; rt < 2; ++rt)
#pragma unroll
                for (int ct = 0; ct < 4; ++ct) {
                    float sec = sse[c16 * 64 + ct * 16 + lr];
                    const int code = c16 * 64 + ct * 16 + lr;
#pragma unroll
                    for (int j = 0; j < 4; ++j) {
                        float dd = __fsub_rn(__fadd_rn(szv[rt][j], sec), 0.03125f * acc[rt][ct][j]);
                        if (dd < d1v[rt][j] || (dd == d1v[rt][j] && code < q1v[rt][j])) {
                            d2v[rt][j] = d1v[rt][j]; q2v[rt][j] = q1v[rt][j];
                            d1v[rt][j] = dd; q1v[rt][j] = code;
                        } else if (dd < d2v[rt][j] || (dd == d2v[rt][j] && code < q2v[rt][j])) {
                            d2v[rt][j] = dd; q2v[rt][j] = code;
                        }
                    }
                }
#pragma unroll
            for (int m = 1; m < 16; m <<= 1)
#pragma unroll
                for (int rt = 0; rt < 2; ++rt)
#pragma unroll
                    for (int j = 0; j < 4; ++j) {
                        float e1 = __shfl_xor(d1v[rt][j], m, 64);
                        float e2 = __shfl_xor(d2v[rt][j], m, 64);
                        int   p1 = __shfl_xor(q1v[rt][j], m, 64);
                        int   p2 = __shfl_xor(q2v[rt][j], m, 64);
                        if (e1 < d1v[rt][j] || (e1 == d1v[rt][j] && p1 < q1v[rt][j])) {
                            // partner's top1 wins; 2nd = lexmin(our top1, partner's top2)
                            if (e2 < d1v[rt][j] || (e2 == d1v[rt][j] && p2 < q1v[rt][j])) {
                                d2v[rt][j] = e2; q2v[rt][j] = p2;
                            } else {
                                d2v[rt][j] = d1v[rt][j]; q2v[rt][j] = q1v[rt][j];
                            }
                            d1v[rt][j] = e1; q1v[rt][j] = p1;
                        } else {
                            // our top1 stays; 2nd = lexmin(our top2, partner's top1)
                            if (e1 < d2v[rt][j] || (e1 == d2v[rt][j] && p1 < q2v[rt][j])) {
                                d2v[rt][j] = e1; q2v[rt][j] = p1;
                            }
                        }
                    }
            if (lr == 0) {
#pragma unroll
                for (int rt = 0; rt < 2; ++rt)
#pragma unroll
                    for (int j = 0; j < 4; ++j) {
                        const size_t o = (size_t)c16 * N_ROWS + wr0 + rt * 16 + lk * 4 + j;
                        cqc1[o] = ((u64)mono32(d1v[rt][j]) << 32) | (u32)q1v[rt][j];
                        cqc2[o] = ((u64)mono32(d2v[rt][j]) << 32) | (u32)q2v[rt][j];
                    }
            }
            __syncthreads();
        }
    }
}

// ---------------- resolve: fastpath + worklists (all 16 chunks) -------------
// Candidates = {chunk top1s, chunk top2s} within W = gmin+2eps. If exactly 1
// (the global best) -> final. Else wl row; chunks whose TOP2 is within W may
// hide rank-3+ codes -> wl2 (row,c16) for full 64-code scan.
__global__ __launch_bounds__(256) void resolve_kernel(
    const float* __restrict__ epsr, const u64* __restrict__ cqc1,
    const u64* __restrict__ cqc2, int* __restrict__ out_idx,
    float* __restrict__ out_idx_f, int* __restrict__ wl, int* __restrict__ wl_cnt,
    int* __restrict__ wl2, int* __restrict__ wl2_cnt) {
    const int row = blockIdx.x * 256 + threadIdx.x;
    const int lane = threadIdx.x & 63;
    u64 k1[NC16], k2[NC16];
    u64 best = ~0ull;
#pragma unroll
    for (int i = 0; i < NC16; ++i) {
        k1[i] = cqc1[(size_t)i * N_ROWS + row];
        k2[i] = cqc2[(size_t)i * N_ROWS + row];
        if (k1[i] < best) best = k1[i];
    }
    const u32 kthr = mono32(fmaf(2.0f, epsr[row], inv_mono((u32)(best >> 32))));
    int ncand = 0;
#pragma unroll
    for (int i = 0; i < NC16; ++i) {
        ncand += ((u32)(k1[i] >> 32) <= kthr);
        ncand += ((u32)(k2[i] >> 32) <= kthr);
    }
    const bool amb = (ncand != 1);
    if (!amb) {
        const int c = (int)(u32)best;
        out_idx[row] = c;
        out_idx_f[row] = (float)c;
    }
    // wl append (wave-aggregated)
    {
        u64 mask = __ballot(amb);
        int cw = __popcll(mask);
        int base = 0;
        if (lane == 0 && cw) base = atomicAdd(wl_cnt, cw);
        base = __shfl(base, 0, 64);
        if (amb) {
            int rank = __popcll(mask & ((1ull << lane) - 1ull));
            wl[base + rank] = row;
        }
    }
    // wl2 appends: flagged chunks of ambiguous rows (16 aggregated rounds)
#pragma unroll 1
    for (int i = 0; i < NC16; ++i) {
        const bool f = amb && ((u32)(k2[i] >> 32) <= kthr);
        u64 mask = __ballot(f);
        int cw = __popcll(mask);
        int base = 0;
        if (lane == 0 && cw) base = atomicAdd(wl2_cnt, cw);
        base = __shfl(base, 0, 64);
        if (f) {
            int rank = __popcll(mask & ((1ull << lane) - 1ull));
            wl2[base + rank] = (row << 4) | i;
        }
    }
}

// ---------------- rescore A: candidate keys of ambiguous rows ---------------
// thread per (wl row, slot 0..31): slot<16 -> cqc1[slot], else cqc2[slot-16].
__global__ __launch_bounds__(256) void rescore_cand_kernel(
    const float* __restrict__ z, const float* __restrict__ e,
    const float* __restrict__ sz, const float* __restrict__ se,
    const float* __restrict__ epsr, const u64* __restrict__ cqc1,
    const u64* __restrict__ cqc2, const int* __restrict__ wl,
    const int* __restrict__ wl_cnt, u64* __restrict__ rkey) {
    const int total = wl_cnt[0] * 32;
    for (int t = blockIdx.x * 256 + threadIdx.x; t < total; t += gridDim.x * 256) {
        const int wi = t >> 5, s = t & 31;
        const int row = wl[wi];
        u32 gm = 0xFFFFFFFFu;
#pragma unroll
        for (int i = 0; i < NC16; ++i)
            gm = min(gm, (u32)(cqc1[(size_t)i * N_ROWS + row] >> 32));
        const u32 kthr = mono32(fmaf(2.0f, epsr[row], inv_mono(gm)));
        const u64 key = (s < 16) ? cqc1[(size_t)s * N_ROWS + row]
                                 : cqc2[(size_t)(s - 16) * N_ROWS + row];
        if ((u32)(key >> 32) <= kthr) {
            const int c = (int)(u32)key;
            float m = exact_dot(z + (size_t)row * ZDIM, e + (size_t)c * ZDIM);
            float d = __fsub_rn(__fadd_rn(sz[row], se[c]), 2.0f * m);
            atomicMin(&rkey[row], ((u64)mono32(d) << 32) | (u32)c);
        }
    }
}

// ---------------- rescore B: full scan of flagged chunks --------------------
// wave per wl2 entry: lane l dots code c16*64+l; in-wave lex-reduce; lane0
// atomicMin. Superset merge is safe (extra codes have exact d >= argmin's).
__global__ __launch_bounds__(256) void rescore_scan_kernel(
    const float* __restrict__ z, const float* __restrict__ e,
    const float* __restrict__ sz, const float* __restrict__ se,
    const int* __restrict__ wl2, const int* __restrict__ wl2_cnt,
    u64* __restrict__ rkey) {
    const int lane = threadIdx.x & 63;
    const int wave = (blockIdx.x * 256 + threadIdx.x) >> 6;
    const int nwaves = (gridDim.x * 256) >> 6;
    const int n = wl2_cnt[0];
    for (int i = wave; i < n; i += nwaves) {
        const int entry = wl2[i];
        const int row = entry >> 4, c16 = entry & 15;
        const int c = c16 * 64 + lane;
        float m = exact_dot(z + (size_t)row * ZDIM, e + (size_t)c * ZDIM);
        float d = __fsub_rn(__fadd_rn(sz[row], se[c]), 2.0f * m);
        u64 key = ((u64)mono32(d) << 32) | (u32)c;
#pragma unroll
        for (int s = 1; s < 64; s <<= 1) {
            u64 ok = __shfl_xor((long long)key, s, 64);
            key = min(key, ok);
        }
        if (lane == 0) atomicMin(&rkey[row], key);
    }
}

// ---------------- rescore C: unpack ambiguous winners ----------------
__global__ __launch_bounds__(256) void rescore_final_kernel(
    const int* __restrict__ wl, const int* __restrict__ wl_cnt,
    const u64* __restrict__ rkey, int* __restrict__ out_idx,
    float* __restrict__ out_idx_f) {
    const int n = wl_cnt[0];
    for (int i = blockIdx.x * 256 + threadIdx.x; i < n; i += gridDim.x * 256) {
        const int row = wl[i];
        const int c = (int)(u32)rkey[row];
        out_idx[row] = c;
        out_idx_f[row] = (float)c;
    }
}

// ---------------- z_q_st + loss partial (no atomics) ----------------
__global__ __launch_bounds__(256) void zq_loss_kernel(
    const float* __restrict__ z, const float* __restrict__ e,
    const int* __restrict__ idx, float* __restrict__ out,
    double* __restrict__ partial) {
    const int tid = threadIdx.x;
    const int rl  = tid >> 6;
    const int ln  = tid & 63;
    const int row0 = blockIdx.x * 32;

    float acc = 0.0f;
#pragma unroll
    for (int it = 0; it < 8; ++it) {
        int row = row0 + it * 4 + rl;
        int code = idx[row];
        const float4 vz = *(const float4*)(z + (size_t)row  * ZDIM + ln * 4);
        const float4 vq = *(const float4*)(e + (size_t)code * ZDIM + ln * 4);
        float4 o;
        float dx = __fsub_rn(vq.x, vz.x);
        float dy = __fsub_rn(vq.y, vz.y);
        float dz_ = __fsub_rn(vq.z, vz.z);
        float dw = __fsub_rn(vq.w, vz.w);
        o.x = __fadd_rn(vz.x, dx);
        o.y = __fadd_rn(vz.y, dy);
        o.z = __fadd_rn(vz.z, dz_);
        o.w = __fadd_rn(vz.w, dw);
        *(float4*)(out + (size_t)row * ZDIM + ln * 4) = o;
        acc = __fadd_rn(acc, __fmul_rn(dx, dx));
        acc = __fadd_rn(acc, __fmul_rn(dy, dy));
        acc = __fadd_rn(acc, __fmul_rn(dz_, dz_));
        acc = __fadd_rn(acc, __fmul_rn(dw, dw));
    }

    __shared__ double red[256];
    red[tid] = (double)acc;
    __syncthreads();
#pragma unroll
    for (int s = 128; s > 0; s >>= 1) {
        if (tid < s) red[tid] += red[tid + s];
        __syncthreads();
    }
    if (tid == 0) partial[blockIdx.x] = red[0];
}

__global__ __launch_bounds__(256) void loss_final_kernel(
    const double* __restrict__ partial, float* __restrict__ out_loss) {
    const int tid = threadIdx.x;
    double s = 0.0;
    for (int i = tid; i < ZQ_BLOCKS; i += 256) s += partial[i];
    __shared__ double red[256];
    red[tid] = s;
    __syncthreads();
#pragma unroll
    for (int st = 128; st > 0; st >>= 1) {
        if (tid < st) red[tid] += red[tid + st];
        __syncthreads();
    }
    if (tid == 0) {
        double M = red[0] / 16777216.0;
        float m32 = (float)M;
        out_loss[0] = __fadd_rn(m32, __fmul_rn(0.25f, m32));
    }
}

extern "C" void kernel_launch(void* const* d_in, const int* in_sizes, int n_in,
                              void* d_out, int out_size, void* d_ws, size_t ws_size,
                              hipStream_t stream) {
    const float* z = (const float*)d_in[0];
    const float* e = (const float*)d_in[1];
    float* out = (float*)d_out;
    char* ws = (char*)d_ws;

    size_t off = 0;
    double* partial = (double*)(ws + off); off += ZQ_BLOCKS * sizeof(double);   // 16 KB
    float*  sz      = (float*) (ws + off); off += (size_t)N_ROWS * 4;           // 256 KB
    float*  epsr    = (float*) (ws + off); off += (size_t)N_ROWS * 4;           // 256 KB
    float*  se      = (float*) (ws + off); off += (size_t)KCODES * 4;           // 4 KB
    int*    idx     = (int*)   (ws + off); off += (size_t)N_ROWS * 4;           // 256 KB
    u16*    ehf     = (u16*)   (ws + off); off += (size_t)KCODES * ZDIM * 2;    // 512 KB
    u64*    cqc1    = (u64*)   (ws + off); off += (size_t)NC16 * N_ROWS * 8;    // 8 MB
    u64*    cqc2    = (u64*)   (ws + off); off += (size_t)NC16 * N_ROWS * 8;    // 8 MB
    int*    wl      = (int*)   (ws + off); off += (size_t)N_ROWS * 4;           // 256 KB
    int*    wl2     = (int*)   (ws + off); off += (size_t)N_ROWS * 4;           // 256 KB
    u64*    rkey    = (u64*)   (ws + off); off += (size_t)N_ROWS * 8;           // 512 KB
    int*    cnts    = (int*)   (ws + off); off += 32;                           // wl_cnt, wl2_cnt
    int* wl_cnt  = cnts;
    int* wl2_cnt = cnts + 1;

    u16* zh = (u16*)out;   // fp16 z in d_out z_q region; zq_loss overwrites later

    hipMemsetAsync(cnts, 0, 32, stream);
    hipMemsetAsync(rkey, 0xFF, (size_t)N_ROWS * 8, stream);
    split_z_kernel<<<8192, 256, 0, stream>>>(z, zh);
    split_e_kernel<<<256, 256, 0, stream>>>(e, ehf);
    rowsq_eps_kernel<<<N_ROWS / 256, 256, 0, stream>>>(z, sz, epsr);
    rowsq_kernel<<<KCODES / 256, 256, 0, stream>>>(e, se, KCODES);
    mfma_argmin_kernel<<<1024, 256, 0, stream>>>(zh, ehf, sz, se, cqc1, cqc2);
    resolve_kernel<<<N_ROWS / 256, 256, 0, stream>>>(epsr, cqc1, cqc2,
                                                     idx, out + IDX_OFF,
                                                     wl, wl_cnt, wl2, wl2_cnt);
    rescore_cand_kernel<<<512, 256, 0, stream>>>(z, e, sz, se, epsr, cqc1, cqc2,
                                                 wl, wl_cnt, rkey);
    rescore_scan_kernel<<<512, 256, 0, stream>>>(z, e, sz, se, wl2, wl2_cnt, rkey);
    rescore_final_kernel<<<256, 256, 0, stream>>>(wl, wl_cnt, rkey, idx, out + IDX_OFF);
    zq_loss_kernel<<<ZQ_BLOCKS, 256, 0, stream>>>(z, e, idx, out, partial);
    loss_final_kernel<<<1, 256, 0, stream>>>(partial, out + LOSS_OFF);
}

// Round 25
// 203.586 us; speedup vs baseline: 5.6355x; 1.5665x over previous
//
#include <hip/hip_runtime.h>
#include <hip/hip_bf16.h>
#include <math.h>

#define N_ROWS 65536
#define ZDIM   256
#define KCODES 1024
#define IDX_OFF  (N_ROWS * ZDIM)        // 16777216
#define LOSS_OFF (IDX_OFF + N_ROWS)     // 16842752
#define ZQ_BLOCKS 2048
#define SLOTS 4
#define NC16 16
#define NC8  8
#define MAXP 16

typedef unsigned int u32;
typedef unsigned short u16;
typedef unsigned long long u64;
typedef __attribute__((ext_vector_type(8))) _Float16 hfrag;  // 8 fp16 (4 VGPR)
typedef __attribute__((ext_vector_type(4))) float ffrag;     // 4 fp32 acc

__device__ __forceinline__ u16 f2h(float x) {
    union { _Float16 h; u16 u; } c; c.h = (_Float16)x; return c.u;   // RN
}

// monotone float->u32 map (total order preserved, incl. negatives)
__device__ __forceinline__ u32 mono32(float d) {
    u32 b = __float_as_uint(d);
    return (b & 0x80000000u) ? ~b : (b | 0x80000000u);
}

// ---------------- numpy-pairwise helpers (256 cols) ----------------
__device__ __forceinline__ float np_pw128_sq(const float* __restrict__ p) {
    float r[8];
#pragma unroll
    for (int j = 0; j < 8; ++j) r[j] = __fmul_rn(p[j], p[j]);
    for (int i = 8; i < 128; i += 8) {
#pragma unroll
        for (int j = 0; j < 8; ++j)
            r[j] = __fadd_rn(r[j], __fmul_rn(p[i + j], p[i + j]));
    }
    float a = __fadd_rn(__fadd_rn(r[0], r[1]), __fadd_rn(r[2], r[3]));
    float b = __fadd_rn(__fadd_rn(r[4], r[5]), __fadd_rn(r[6], r[7]));
    return __fadd_rn(a, b);
}

// exact OpenBLAS-order dot, float4 loads (same fmaf sequence)
__device__ __forceinline__ float exact_dot(const float* __restrict__ zr,
                                           const float* __restrict__ er) {
    float m = 0.0f;
#pragma unroll 4
    for (int k = 0; k < ZDIM; k += 4) {
        float4 a = *(const float4*)(zr + k);
        float4 b = *(const float4*)(er + k);
        m = fmaf(a.x, b.x, m);
        m = fmaf(a.y, b.y, m);
        m = fmaf(a.z, b.z, m);
        m = fmaf(a.w, b.w, m);
    }
    return m;
}

// se for e rows (np-exact)
__global__ void rowsq_kernel(const float* __restrict__ x, float* __restrict__ s, int nrows) {
    int r = blockIdx.x * blockDim.x + threadIdx.x;
    if (r >= nrows) return;
    const float* p = x + (size_t)r * ZDIM;
    s[r] = __fadd_rn(np_pw128_sq(p), np_pw128_sq(p + 128));
}

// ---------------- fused z prep: zh (fp16), sz, epsr in ONE z pass -----------
// Block: 32 rows. Coalesced load -> LDS (stride 260 pads banks). fp16 pack
// stored coalesced. Sums: 8 threads/row, thread j owns np accumulator r[j]
// (independent strided chain, order-exact); xor-shuffle tree reproduces
// ((r0+r1)+(r2+r3))+((r4+r5)+(r6+r7)) bit-exactly (IEEE add commutative,
// identical pairings). sz = fadd(halfA, halfB); S1 likewise for epsr.
__global__ __launch_bounds__(256) void prep_z_kernel(
    const float* __restrict__ z, u16* __restrict__ zh,
    float* __restrict__ sz, float* __restrict__ epsr) {
    __shared__ float zbuf[32 * 260];   // 33.3 KB
    const int t = threadIdx.x;
    const int row0 = blockIdx.x * 32;
    // load 32 rows coalesced
#pragma unroll
    for (int it = 0; it < 8; ++it) {
        int f = it * 256 + t;              // float4 index 0..2047
        int row = f >> 6, col4 = f & 63;
        float4 v = *(const float4*)(z + (size_t)(row0 + row) * ZDIM + col4 * 4);
        float* d = zbuf + row * 260 + col4 * 4;
        d[0] = v.x; d[1] = v.y; d[2] = v.z; d[3] = v.w;
    }
    __syncthreads();
    // fp16 convert + pack (coalesced stores)
#pragma unroll
    for (int it = 0; it < 4; ++it) {
        int u = it * 256 + t;              // uint4 index (8 elems)
        int row = u >> 5, col8 = u & 31;
        const float* p = zbuf + row * 260 + col8 * 8;
        uint4 w;
        w.x = ((u32)f2h(p[1]) << 16) | f2h(p[0]);
        w.y = ((u32)f2h(p[3]) << 16) | f2h(p[2]);
        w.z = ((u32)f2h(p[5]) << 16) | f2h(p[4]);
        w.w = ((u32)f2h(p[7]) << 16) | f2h(p[6]);
        *(uint4*)(zh + (size_t)(row0 + row) * ZDIM + col8 * 8) = w;
    }
    // sums: group g = t>>3 (row), lane j = t&7 owns accumulator j
    {
        const int g = t >> 3, j = t & 7;
        const float* p = zbuf + g * 260;
        float rA, rB, aA, aB;
        {
            float x = p[j];        rA = __fmul_rn(x, x); aA = fabsf(x);
            float y = p[128 + j];  rB = __fmul_rn(y, y); aB = fabsf(y);
        }
#pragma unroll
        for (int i = 8; i < 128; i += 8) {
            float x = p[i + j];
            rA = __fadd_rn(rA, __fmul_rn(x, x));
            aA = aA + fabsf(x);
            float y = p[128 + i + j];
            rB = __fadd_rn(rB, __fmul_rn(y, y));
            aB = aB + fabsf(y);
        }
        // xor-shuffle tree (within 8-lane group)
        rA = __fadd_rn(rA, __shfl_xor(rA, 1, 64));
        rB = __fadd_rn(rB, __shfl_xor(rB, 1, 64));
        aA = aA + __shfl_xor(aA, 1, 64);
        aB = aB + __shfl_xor(aB, 1, 64);
        rA = __fadd_rn(rA, __shfl_xor(rA, 2, 64));
        rB = __fadd_rn(rB, __shfl_xor(rB, 2, 64));
        aA = aA + __shfl_xor(aA, 2, 64);
        aB = aB + __shfl_xor(aB, 2, 64);
        rA = __fadd_rn(rA, __shfl_xor(rA, 4, 64));
        rB = __fadd_rn(rB, __shfl_xor(rB, 4, 64));
        aA = aA + __shfl_xor(aA, 4, 64);
        aB = aB + __shfl_xor(aB, 4, 64);
        if (j == 0) {
            sz[row0 + g]   = __fadd_rn(rA, rB);
            epsr[row0 + g] = fmaf(aA + aB, 1.1e-6f, 6e-5f);
        }
    }
}

// ---------------- e -> fp16 scaled x64, FRAGMENT-MAJOR layout ----------------
__global__ __launch_bounds__(256) void split_e_kernel(
    const float* __restrict__ e, u16* __restrict__ ehf) {
    int t = blockIdx.x * 256 + threadIdx.x;      // 65536 threads
    int c = t >> 6, kq = t & 63;                 // dims kq*4 .. +3
    float4 v = *(const float4*)(e + (size_t)c * ZDIM + kq * 4);
    ushort4 h;
    h.x = f2h(v.x * 64.0f); h.y = f2h(v.y * 64.0f);
    h.z = f2h(v.z * 64.0f); h.w = f2h(v.w * 64.0f);
    int c16 = c >> 6, ct = (c >> 4) & 3, lr = c & 15;
    int kc = kq >> 3, lk = (kq >> 1) & 3;
    int lane = lk * 16 + lr;
    size_t base = ((size_t)((c16 * 8 + kc) * 4 + ct) * 64 + lane) * 8 + ((kq * 4) & 7);
    *(ushort4*)(ehf + base) = h;
}

// ---------------- LDS-shared fp16 MFMA (r21-exact: ballot emission) ---------
__global__ __launch_bounds__(256) void mfma_argmin_kernel(
    const u16* __restrict__ zh, const u16* __restrict__ ehf,
    const float* __restrict__ sz, const float* __restrict__ se,
    const float* __restrict__ epsr, float* __restrict__ cqmin,
    int* __restrict__ cnt, float* __restrict__ cand_d, int* __restrict__ cand_i) {
    __shared__ __align__(16) char ehL[2][16384];      // 32 KB (double buffer)
    __shared__ float sse[KCODES];                     // 4 KB
    const int tid = threadIdx.x;
    const int lane = tid & 63;
    const int lr = lane & 15, lk = lane >> 4;
    const int rp = blockIdx.x >> 1, cp = blockIdx.x & 1;
    const int wr0 = rp * 128 + (tid >> 6) * 32;

    *(float4*)(sse + tid * 4) = *(const float4*)(se + tid * 4);

    float szv[2][4], epsv[2][4];
#pragma unroll
    for (int rt = 0; rt < 2; ++rt)
#pragma unroll
        for (int j = 0; j < 4; ++j) {
            szv[rt][j]  = sz[wr0 + rt * 16 + lk * 4 + j];
            epsv[rt][j] = epsr[wr0 + rt * 16 + lk * 4 + j];
        }

    hfrag A[2][8];
#pragma unroll
    for (int rt = 0; rt < 2; ++rt)
#pragma unroll
        for (int kc = 0; kc < 8; ++kc)
            A[rt][kc] = *(const hfrag*)(zh + (size_t)(wr0 + rt * 16 + lr) * ZDIM + kc * 32 + lk * 8);

    const char* ehpb = (const char*)ehf + (size_t)cp * 8 * 32768;  // this cp half

    // prologue: stage segment 0 into buf0
    {
        const char* src = ehpb;
        uint4 s0 = *(const uint4*)(src + tid * 16);
        uint4 s1 = *(const uint4*)(src + 4096 + tid * 16);
        uint4 s2 = *(const uint4*)(src + 8192 + tid * 16);
        uint4 s3 = *(const uint4*)(src + 12288 + tid * 16);
        *(uint4*)(&ehL[0][tid * 16])         = s0;
        *(uint4*)(&ehL[0][4096 + tid * 16])  = s1;
        *(uint4*)(&ehL[0][8192 + tid * 16])  = s2;
        *(uint4*)(&ehL[0][12288 + tid * 16]) = s3;
    }
    __syncthreads();   // seg0 staged; also covers sse init

    ffrag acc[2][4];
    int bcnt[2][4];    // per-row emission count, carried across each c8 pair

#pragma unroll 1
    for (int cc = 0; cc < 8; ++cc) {
        const int c16 = cp * 8 + cc;
        const int c8  = c16 >> 1;

        // ===== phase h=0: compute seg 2cc (buf0, kc 0..3); stage 2cc+1 -> buf1
        {
#pragma unroll
            for (int rt = 0; rt < 2; ++rt)
#pragma unroll
                for (int ct = 0; ct < 4; ++ct) acc[rt][ct] = (ffrag)(0.0f);
            const char* src = ehpb + (size_t)(2 * cc + 1) * 16384;
            uint4 s0 = *(const uint4*)(src + tid * 16);
            uint4 s1 = *(const uint4*)(src + 4096 + tid * 16);
            uint4 s2 = *(const uint4*)(src + 8192 + tid * 16);
            uint4 s3 = *(const uint4*)(src + 12288 + tid * 16);
            const char* buf = ehL[0];
#pragma unroll
            for (int kcl = 0; kcl < 4; ++kcl) {
#pragma unroll
                for (int ct = 0; ct < 4; ++ct) {
                    hfrag bh = *(const hfrag*)(buf + (size_t)(kcl * 4 + ct) * 1024 + (size_t)lane * 16);
                    acc[0][ct] = __builtin_amdgcn_mfma_f32_16x16x32_f16(A[0][kcl], bh, acc[0][ct], 0, 0, 0);
                    acc[1][ct] = __builtin_amdgcn_mfma_f32_16x16x32_f16(A[1][kcl], bh, acc[1][ct], 0, 0, 0);
                }
            }
            char* dst = ehL[1];
            *(uint4*)(dst + tid * 16)         = s0;
            *(uint4*)(dst + 4096 + tid * 16)  = s1;
            *(uint4*)(dst + 8192 + tid * 16)  = s2;
            *(uint4*)(dst + 12288 + tid * 16) = s3;
            __syncthreads();
        }

        // ===== phase h=1: compute seg 2cc+1 (buf1, kc 4..7); stage 2cc+2 -> buf0
        {
            uint4 s0, s1, s2, s3;
            const bool more = (cc < 7);
            if (more) {
                const char* src = ehpb + (size_t)(2 * cc + 2) * 16384;
                s0 = *(const uint4*)(src + tid * 16);
                s1 = *(const uint4*)(src + 4096 + tid * 16);
                s2 = *(const uint4*)(src + 8192 + tid * 16);
                s3 = *(const uint4*)(src + 12288 + tid * 16);
            }
            const char* buf = ehL[1];
#pragma unroll
            for (int kcl = 0; kcl < 4; ++kcl) {
#pragma unroll
                for (int ct = 0; ct < 4; ++ct) {
                    hfrag bh = *(const hfrag*)(buf + (size_t)(kcl * 4 + ct) * 1024 + (size_t)lane * 16);
                    acc[0][ct] = __builtin_amdgcn_mfma_f32_16x16x32_f16(A[0][4 + kcl], bh, acc[0][ct], 0, 0, 0);
                    acc[1][ct] = __builtin_amdgcn_mfma_f32_16x16x32_f16(A[1][4 + kcl], bh, acc[1][ct], 0, 0, 0);
                }
            }
            if (more) {
                char* dst = ehL[0];
                *(uint4*)(dst + tid * 16)         = s0;
                *(uint4*)(dst + 4096 + tid * 16)  = s1;
                *(uint4*)(dst + 8192 + tid * 16)  = s2;
                *(uint4*)(dst + 12288 + tid * 16) = s3;
            }

            // ---- epilogue for c16: d~ = fl(fl(sz+se) - acc/32) ----
            float rmin[2][4];
#pragma unroll
            for (int rt = 0; rt < 2; ++rt)
#pragma unroll
                for (int j = 0; j < 4; ++j) rmin[rt][j] = __builtin_inff();
#pragma unroll
            for (int rt = 0; rt < 2; ++rt)
#pragma unroll
                for (int ct = 0; ct < 4; ++ct) {
                    float sec = sse[c16 * 64 + ct * 16 + lr];
#pragma unroll
                    for (int j = 0; j < 4; ++j) {
                        float dd = __fsub_rn(__fadd_rn(szv[rt][j], sec), 0.03125f * acc[rt][ct][j]);
                        rmin[rt][j] = fminf(rmin[rt][j], dd);
                    }
                }
#pragma unroll
            for (int m = 1; m < 16; m <<= 1)
#pragma unroll
                for (int rt = 0; rt < 2; ++rt)
#pragma unroll
                    for (int j = 0; j < 4; ++j)
                        rmin[rt][j] = fminf(rmin[rt][j], __shfl_xor(rmin[rt][j], m, 64));
            if (lr == 0) {
#pragma unroll
                for (int rt = 0; rt < 2; ++rt)
#pragma unroll
                    for (int j = 0; j < 4; ++j)
                        cqmin[(size_t)(wr0 + rt * 16 + lk * 4 + j) * NC16 + c16] = rmin[rt][j];
            }
            // ---- ballot-based emission (no atomics) ----
            if ((cc & 1) == 0) {
#pragma unroll
                for (int rt = 0; rt < 2; ++rt)
#pragma unroll
                    for (int j = 0; j < 4; ++j) bcnt[rt][j] = 0;
            }
#pragma unroll
            for (int rt = 0; rt < 2; ++rt)
#pragma unroll
                for (int j = 0; j < 4; ++j) {
                    const float thr = fmaf(2.0f, epsv[rt][j], rmin[rt][j]);
                    const int grow = wr0 + rt * 16 + lk * 4 + j;
#pragma unroll
                    for (int ct = 0; ct < 4; ++ct) {
                        float dd = __fsub_rn(__fadd_rn(szv[rt][j], sse[c16 * 64 + ct * 16 + lr]),
                                             0.03125f * acc[rt][ct][j]);
                        const bool emit = (dd <= thr);
                        u64 bal = __ballot(emit);
                        u32 grp = (u32)(bal >> (lk * 16)) & 0xFFFFu;
                        if (emit) {
                            int slot = bcnt[rt][j] + __popc(grp & ((1u << lr) - 1u));
                            if (slot < SLOTS) {
                                size_t base = ((size_t)grow * NC8 + c8) * SLOTS + slot;
                                cand_i[base] = c16 * 64 + ct * 16 + lr;
                                cand_d[base] = dd;
                            }
                        }
                        bcnt[rt][j] += __popc(grp);
                    }
                }
            if (cc & 1) {
                if (lr == 0) {
#pragma unroll
                    for (int rt = 0; rt < 2; ++rt)
#pragma unroll
                        for (int j = 0; j < 4; ++j)
                            cnt[(size_t)(wr0 + rt * 16 + lk * 4 + j) * NC8 + c8] = bcnt[rt][j];
                }
            }
            __syncthreads();
        }
    }
}

// ---------------- rescore stage 1: filter + fastpath + two worklists --------
__global__ __launch_bounds__(256) void rescore_fast_kernel(
    const float* __restrict__ epsr, const float* __restrict__ cqmin,
    const int* __restrict__ cnt, const float* __restrict__ cand_d,
    const int* __restrict__ cand_i, int* __restrict__ out_idx,
    float* __restrict__ out_idx_f, int* __restrict__ wl, int* __restrict__ wl_cnt,
    int* __restrict__ wl2, int* __restrict__ wl2_cnt,
    int* __restrict__ np, int* __restrict__ pc) {
    const int row = blockIdx.x * 256 + threadIdx.x;
    const int lane = threadIdx.x & 63;
    float cq[NC16];
#pragma unroll
    for (int i = 0; i < 4; ++i)
        *(float4*)&cq[i * 4] = *(const float4*)(cqmin + (size_t)row * NC16 + i * 4);
    float gmin = __builtin_inff();
#pragma unroll
    for (int i = 0; i < NC16; ++i) gmin = fminf(gmin, cq[i]);
    const float thr = fmaf(2.0f, epsr[row], gmin);

    int nc = 0, first_c = 0;
    bool scan = false;
#pragma unroll
    for (int c8 = 0; c8 < NC8; ++c8) {
        if (fminf(cq[2 * c8], cq[2 * c8 + 1]) > thr) continue;
        int n = cnt[(size_t)row * NC8 + c8];
        if (n > SLOTS) { scan = true; }
        else {
            for (int s = 0; s < n; ++s) {
                size_t base = ((size_t)row * NC8 + c8) * SLOTS + s;
                if (cand_d[base] <= thr) {
                    int c = cand_i[base];
                    if (nc == 0) first_c = c;
                    if (nc < MAXP) pc[(size_t)row * MAXP + nc] = c;
                    ++nc;
                }
            }
        }
    }
    if (nc > MAXP) scan = true;
    const bool fast = !scan && nc == 1;
    const bool pair = !scan && nc != 1;
    if (fast) {
        out_idx[row] = first_c;
        out_idx_f[row] = (float)first_c;
    } else if (pair) {
        np[row] = nc;
    }
    {
        u64 mask = __ballot(pair);
        int cw = __popcll(mask);
        int base = 0;
        if (lane == 0 && cw) base = atomicAdd(wl_cnt, cw);
        base = __shfl(base, 0, 64);
        if (pair) {
            int rank = __popcll(mask & ((1ull << lane) - 1ull));
            wl[base + rank] = row;
        }
    }
    {
        u64 mask = __ballot(scan);
        int cw = __popcll(mask);
        int base = 0;
        if (lane == 0 && cw) base = atomicAdd(wl2_cnt, cw);
        base = __shfl(base, 0, 64);
        if (scan) {
            int rank = __popcll(mask & ((1ull << lane) - 1ull));
            wl2[base + rank] = row;
        }
    }
}

// ---------------- rescore stage 2a: thread-per-(pair-row, candidate) --------
__global__ __launch_bounds__(256) void rescore_pair_kernel(
    const float* __restrict__ z, const float* __restrict__ e,
    const float* __restrict__ sz, const float* __restrict__ se,
    const int* __restrict__ np, const int* __restrict__ pc,
    const int* __restrict__ wl, const int* __restrict__ wl_cnt,
    u64* __restrict__ rkey) {
    const int total = wl_cnt[0] * MAXP;
    for (int t = blockIdx.x * 256 + threadIdx.x; t < total; t += gridDim.x * 256) {
        const int wi = t >> 4, j = t & 15;
        const int row = wl[wi];
        if (j >= np[row]) continue;
        int c = pc[(size_t)row * MAXP + j];
        float m = exact_dot(z + (size_t)row * ZDIM, e + (size_t)c * ZDIM);
        float d = __fsub_rn(__fadd_rn(sz[row], se[c]), 2.0f * m);
        u64 key = ((u64)mono32(d) << 32) | (u32)c;
        atomicMin(&rkey[row], key);
    }
}

// ---------------- rescore stage 2b: thread-per-(scan-row, code) -------------
__global__ __launch_bounds__(256) void rescore_scan_kernel(
    const float* __restrict__ z, const float* __restrict__ e,
    const float* __restrict__ sz, const float* __restrict__ se,
    const float* __restrict__ epsr, const float* __restrict__ cqmin,
    const int* __restrict__ wl2, const int* __restrict__ wl2_cnt,
    u64* __restrict__ rkey) {
    const int total = wl2_cnt[0] * KCODES;
    for (int t = blockIdx.x * 256 + threadIdx.x; t < total; t += gridDim.x * 256) {
        const int si = t >> 10, c = t & 1023;
        const int row = wl2[si];
        float gmin = __builtin_inff();
#pragma unroll
        for (int i = 0; i < NC16; ++i)
            gmin = fminf(gmin, cqmin[(size_t)row * NC16 + i]);
        const float thr = fmaf(2.0f, epsr[row], gmin);
        const int c8 = c >> 7;
        if (fminf(cqmin[(size_t)row * NC16 + 2 * c8],
                  cqmin[(size_t)row * NC16 + 2 * c8 + 1]) > thr) continue;
        float m = exact_dot(z + (size_t)row * ZDIM, e + (size_t)c * ZDIM);
        float d = __fsub_rn(__fadd_rn(sz[row], se[c]), 2.0f * m);
        u64 key = ((u64)mono32(d) << 32) | (u32)c;
        atomicMin(&rkey[row], key);
    }
}

// ---------------- rescore stage 3: unpack winners (both lists) --------------
__global__ __launch_bounds__(256) void rescore_final_kernel(
    const int* __restrict__ wl, const int* __restrict__ wl_cnt,
    const int* __restrict__ wl2, const int* __restrict__ wl2_cnt,
    const u64* __restrict__ rkey, int* __restrict__ out_idx,
    float* __restrict__ out_idx_f) {
    const int i = blockIdx.x * 256 + threadIdx.x;
    const int n1 = wl_cnt[0], n2 = wl2_cnt[0];
    if (i < n1 + n2) {
        const int row = (i < n1) ? wl[i] : wl2[i - n1];
        const int c = (int)(u32)rkey[row];
        out_idx[row] = c;
        out_idx_f[row] = (float)c;
    }
}

// ---------------- z_q_st + loss partial (no atomics) ----------------
__global__ __launch_bounds__(256) void zq_loss_kernel(
    const float* __restrict__ z, const float* __restrict__ e,
    const int* __restrict__ idx, float* __restrict__ out,
    double* __restrict__ partial) {
    const int tid = threadIdx.x;
    const int rl  = tid >> 6;
    const int ln  = tid & 63;
    const int row0 = blockIdx.x * 32;

    float acc = 0.0f;
#pragma unroll
    for (int it = 0; it < 8; ++it) {
        int row = row0 + it * 4 + rl;
        int code = idx[row];
        const float4 vz = *(const float4*)(z + (size_t)row  * ZDIM + ln * 4);
        const float4 vq = *(const float4*)(e + (size_t)code * ZDIM + ln * 4);
        float4 o;
        float dx = __fsub_rn(vq.x, vz.x);
        float dy = __fsub_rn(vq.y, vz.y);
        float dz_ = __fsub_rn(vq.z, vz.z);
        float dw = __fsub_rn(vq.w, vz.w);
        o.x = __fadd_rn(vz.x, dx);
        o.y = __fadd_rn(vz.y, dy);
        o.z = __fadd_rn(vz.z, dz_);
        o.w = __fadd_rn(vz.w, dw);
        *(float4*)(out + (size_t)row * ZDIM + ln * 4) = o;
        acc = __fadd_rn(acc, __fmul_rn(dx, dx));
        acc = __fadd_rn(acc, __fmul_rn(dy, dy));
        acc = __fadd_rn(acc, __fmul_rn(dz_, dz_));
        acc = __fadd_rn(acc, __fmul_rn(dw, dw));
    }

    __shared__ double red[256];
    red[tid] = (double)acc;
    __syncthreads();
#pragma unroll
    for (int s = 128; s > 0; s >>= 1) {
        if (tid < s) red[tid] += red[tid + s];
        __syncthreads();
    }
    if (tid == 0) partial[blockIdx.x] = red[0];
}

__global__ __launch_bounds__(256) void loss_final_kernel(
    const double* __restrict__ partial, float* __restrict__ out_loss) {
    const int tid = threadIdx.x;
    double s = 0.0;
    for (int i = tid; i < ZQ_BLOCKS; i += 256) s += partial[i];
    __shared__ double red[256];
    red[tid] = s;
    __syncthreads();
#pragma unroll
    for (int st = 128; st > 0; st >>= 1) {
        if (tid < st) red[tid] += red[tid + st];
        __syncthreads();
    }
    if (tid == 0) {
        double M = red[0] / 16777216.0;
        float m32 = (float)M;
        out_loss[0] = __fadd_rn(m32, __fmul_rn(0.25f, m32));
    }
}

extern "C" void kernel_launch(void* const* d_in, const int* in_sizes, int n_in,
                              void* d_out, int out_size, void* d_ws, size_t ws_size,
                              hipStream_t stream) {
    const float* z = (const float*)d_in[0];
    const float* e = (const float*)d_in[1];
    float* out = (float*)d_out;
    char* ws = (char*)d_ws;

    size_t off = 0;
    double* partial = (double*)(ws + off); off += ZQ_BLOCKS * sizeof(double);        // 16 KB
    float*  sz      = (float*) (ws + off); off += (size_t)N_ROWS * 4;                // 256 KB
    float*  epsr    = (float*) (ws + off); off += (size_t)N_ROWS * 4;                // 256 KB
    float*  se      = (float*) (ws + off); off += (size_t)KCODES * 4;                // 4 KB
    int*    idx     = (int*)   (ws + off); off += (size_t)N_ROWS * 4;                // 256 KB
    u16*    ehf     = (u16*)   (ws + off); off += (size_t)KCODES * ZDIM * 2;         // 512 KB
    float*  cqmin   = (float*) (ws + off); off += (size_t)N_ROWS * NC16 * 4;         // 4 MB
    int*    cnt     = (int*)   (ws + off); off += (size_t)N_ROWS * NC8 * 4;          // 2 MB
    float*  cand_d  = (float*) (ws + off); off += (size_t)N_ROWS * NC8 * SLOTS * 4;  // 8 MB
    int*    cand_i  = (int*)   (ws + off); off += (size_t)N_ROWS * NC8 * SLOTS * 4;  // 8 MB
    int*    wl      = (int*)   (ws + off); off += (size_t)N_ROWS * 4;                // 256 KB
    int*    wl2     = (int*)   (ws + off); off += (size_t)N_ROWS * 4;                // 256 KB
    int*    np      = (int*)   (ws + off); off += (size_t)N_ROWS * 4;                // 256 KB
    int*    pc      = (int*)   (ws + off); off += (size_t)N_ROWS * MAXP * 4;         // 4 MB
    u64*    rkey    = (u64*)   (ws + off); off += (size_t)N_ROWS * 8;                // 512 KB
    int*    wl_cnt  = (int*)   (ws + off); off += 16;
    int*    wl2_cnt = (int*)   (ws + off); off += 16;

    u16* zh = (u16*)out;   // fp16 z in d_out z_q region; zq_loss overwrites later

    hipMemsetAsync(wl_cnt, 0, 32, stream);
    hipMemsetAsync(rkey, 0xFF, (size_t)N_ROWS * 8, stream);
    prep_z_kernel<<<N_ROWS / 32, 256, 0, stream>>>(z, zh, sz, epsr);
    split_e_kernel<<<256, 256, 0, stream>>>(e, ehf);
    rowsq_kernel<<<KCODES / 256, 256, 0, stream>>>(e, se, KCODES);
    mfma_argmin_kernel<<<1024, 256, 0, stream>>>(zh, ehf, sz, se, epsr, cqmin, cnt, cand_d, cand_i);
    rescore_fast_kernel<<<N_ROWS / 256, 256, 0, stream>>>(epsr, cqmin, cnt, cand_d, cand_i,
                                                          idx, out + IDX_OFF, wl, wl_cnt,
                                                          wl2, wl2_cnt, np, pc);
    rescore_pair_kernel<<<1024, 256, 0, stream>>>(z, e, sz, se, np, pc, wl, wl_cnt, rkey);
    rescore_scan_kernel<<<1024, 256, 0, stream>>>(z, e, sz, se, epsr, cqmin, wl2, wl2_cnt, rkey);
    rescore_final_kernel<<<N_ROWS / 256, 256, 0, stream>>>(wl, wl_cnt, wl2, wl2_cnt, rkey,
                                                           idx, out + IDX_OFF);
    zq_loss_kernel<<<ZQ_BLOCKS, 256, 0, stream>>>(z, e, idx, out, partial);
    loss_final_kernel<<<1, 256, 0, stream>>>(partial, out + LOSS_OFF);
}

// Round 26
// 200.712 us; speedup vs baseline: 5.7161x; 1.0143x over previous
//
#include <hip/hip_runtime.h>
#include <hip/hip_bf16.h>
#include <math.h>

#define N_ROWS 65536
#define ZDIM   256
#define KCODES 1024
#define IDX_OFF  (N_ROWS * ZDIM)        // 16777216
#define LOSS_OFF (IDX_OFF + N_ROWS)     // 16842752
#define ZQ_BLOCKS 2048
#define SLOTS 4
#define NC16 16
#define NC8  8
#define MAXP 16

typedef unsigned int u32;
typedef unsigned short u16;
typedef unsigned long long u64;
typedef __attribute__((ext_vector_type(8))) _Float16 hfrag;  // 8 fp16 (4 VGPR)
typedef __attribute__((ext_vector_type(4))) float ffrag;     // 4 fp32 acc

__device__ __forceinline__ u16 f2h(float x) {
    union { _Float16 h; u16 u; } c; c.h = (_Float16)x; return c.u;   // RN
}

// monotone float->u32 map (total order preserved, incl. negatives)
__device__ __forceinline__ u32 mono32(float d) {
    u32 b = __float_as_uint(d);
    return (b & 0x80000000u) ? ~b : (b | 0x80000000u);
}

// ---------------- numpy-pairwise helpers (256 cols) ----------------
__device__ __forceinline__ float np_pw128_sq(const float* __restrict__ p) {
    float r[8];
#pragma unroll
    for (int j = 0; j < 8; ++j) r[j] = __fmul_rn(p[j], p[j]);
    for (int i = 8; i < 128; i += 8) {
#pragma unroll
        for (int j = 0; j < 8; ++j)
            r[j] = __fadd_rn(r[j], __fmul_rn(p[i + j], p[i + j]));
    }
    float a = __fadd_rn(__fadd_rn(r[0], r[1]), __fadd_rn(r[2], r[3]));
    float b = __fadd_rn(__fadd_rn(r[4], r[5]), __fadd_rn(r[6], r[7]));
    return __fadd_rn(a, b);
}

// exact OpenBLAS-order dot, float4 loads (same fmaf sequence)
__device__ __forceinline__ float exact_dot(const float* __restrict__ zr,
                                           const float* __restrict__ er) {
    float m = 0.0f;
#pragma unroll 4
    for (int k = 0; k < ZDIM; k += 4) {
        float4 a = *(const float4*)(zr + k);
        float4 b = *(const float4*)(er + k);
        m = fmaf(a.x, b.x, m);
        m = fmaf(a.y, b.y, m);
        m = fmaf(a.z, b.z, m);
        m = fmaf(a.w, b.w, m);
    }
    return m;
}

// se for e rows (np-exact)
__global__ void rowsq_kernel(const float* __restrict__ x, float* __restrict__ s, int nrows) {
    int r = blockIdx.x * blockDim.x + threadIdx.x;
    if (r >= nrows) return;
    const float* p = x + (size_t)r * ZDIM;
    s[r] = __fadd_rn(np_pw128_sq(p), np_pw128_sq(p + 128));
}

// ---------------- fused z prep: zh (fp16), sz, epsr in ONE z pass -----------
__global__ __launch_bounds__(256) void prep_z_kernel(
    const float* __restrict__ z, u16* __restrict__ zh,
    float* __restrict__ sz, float* __restrict__ epsr) {
    __shared__ float zbuf[32 * 260];   // 33.3 KB
    const int t = threadIdx.x;
    const int row0 = blockIdx.x * 32;
#pragma unroll
    for (int it = 0; it < 8; ++it) {
        int f = it * 256 + t;
        int row = f >> 6, col4 = f & 63;
        float4 v = *(const float4*)(z + (size_t)(row0 + row) * ZDIM + col4 * 4);
        float* d = zbuf + row * 260 + col4 * 4;
        d[0] = v.x; d[1] = v.y; d[2] = v.z; d[3] = v.w;
    }
    __syncthreads();
#pragma unroll
    for (int it = 0; it < 4; ++it) {
        int u = it * 256 + t;
        int row = u >> 5, col8 = u & 31;
        const float* p = zbuf + row * 260 + col8 * 8;
        uint4 w;
        w.x = ((u32)f2h(p[1]) << 16) | f2h(p[0]);
        w.y = ((u32)f2h(p[3]) << 16) | f2h(p[2]);
        w.z = ((u32)f2h(p[5]) << 16) | f2h(p[4]);
        w.w = ((u32)f2h(p[7]) << 16) | f2h(p[6]);
        *(uint4*)(zh + (size_t)(row0 + row) * ZDIM + col8 * 8) = w;
    }
    {
        const int g = t >> 3, j = t & 7;
        const float* p = zbuf + g * 260;
        float rA, rB, aA, aB;
        {
            float x = p[j];        rA = __fmul_rn(x, x); aA = fabsf(x);
            float y = p[128 + j];  rB = __fmul_rn(y, y); aB = fabsf(y);
        }
#pragma unroll
        for (int i = 8; i < 128; i += 8) {
            float x = p[i + j];
            rA = __fadd_rn(rA, __fmul_rn(x, x));
            aA = aA + fabsf(x);
            float y = p[128 + i + j];
            rB = __fadd_rn(rB, __fmul_rn(y, y));
            aB = aB + fabsf(y);
        }
        rA = __fadd_rn(rA, __shfl_xor(rA, 1, 64));
        rB = __fadd_rn(rB, __shfl_xor(rB, 1, 64));
        aA = aA + __shfl_xor(aA, 1, 64);
        aB = aB + __shfl_xor(aB, 1, 64);
        rA = __fadd_rn(rA, __shfl_xor(rA, 2, 64));
        rB = __fadd_rn(rB, __shfl_xor(rB, 2, 64));
        aA = aA + __shfl_xor(aA, 2, 64);
        aB = aB + __shfl_xor(aB, 2, 64);
        rA = __fadd_rn(rA, __shfl_xor(rA, 4, 64));
        rB = __fadd_rn(rB, __shfl_xor(rB, 4, 64));
        aA = aA + __shfl_xor(aA, 4, 64);
        aB = aB + __shfl_xor(aB, 4, 64);
        if (j == 0) {
            sz[row0 + g]   = __fadd_rn(rA, rB);
            epsr[row0 + g] = fmaf(aA + aB, 1.1e-6f, 6e-5f);
        }
    }
}

// ---------------- e -> fp16 scaled x64, FRAGMENT-MAJOR layout ----------------
__global__ __launch_bounds__(256) void split_e_kernel(
    const float* __restrict__ e, u16* __restrict__ ehf) {
    int t = blockIdx.x * 256 + threadIdx.x;      // 65536 threads
    int c = t >> 6, kq = t & 63;                 // dims kq*4 .. +3
    float4 v = *(const float4*)(e + (size_t)c * ZDIM + kq * 4);
    ushort4 h;
    h.x = f2h(v.x * 64.0f); h.y = f2h(v.y * 64.0f);
    h.z = f2h(v.z * 64.0f); h.w = f2h(v.w * 64.0f);
    int c16 = c >> 6, ct = (c >> 4) & 3, lr = c & 15;
    int kc = kq >> 3, lk = (kq >> 1) & 3;
    int lane = lk * 16 + lr;
    size_t base = ((size_t)((c16 * 8 + kc) * 4 + ct) * 64 + lane) * 8 + ((kq * 4) & 7);
    *(ushort4*)(ehf + base) = h;
}

// ---------------- LDS-shared fp16 MFMA (r21-exact: ballot emission) ---------
__global__ __launch_bounds__(256) void mfma_argmin_kernel(
    const u16* __restrict__ zh, const u16* __restrict__ ehf,
    const float* __restrict__ sz, const float* __restrict__ se,
    const float* __restrict__ epsr, float* __restrict__ cqmin,
    int* __restrict__ cnt, float* __restrict__ cand_d, int* __restrict__ cand_i) {
    __shared__ __align__(16) char ehL[2][16384];      // 32 KB (double buffer)
    __shared__ float sse[KCODES];                     // 4 KB
    const int tid = threadIdx.x;
    const int lane = tid & 63;
    const int lr = lane & 15, lk = lane >> 4;
    const int rp = blockIdx.x >> 1, cp = blockIdx.x & 1;
    const int wr0 = rp * 128 + (tid >> 6) * 32;

    *(float4*)(sse + tid * 4) = *(const float4*)(se + tid * 4);

    float szv[2][4], epsv[2][4];
#pragma unroll
    for (int rt = 0; rt < 2; ++rt)
#pragma unroll
        for (int j = 0; j < 4; ++j) {
            szv[rt][j]  = sz[wr0 + rt * 16 + lk * 4 + j];
            epsv[rt][j] = epsr[wr0 + rt * 16 + lk * 4 + j];
        }

    hfrag A[2][8];
#pragma unroll
    for (int rt = 0; rt < 2; ++rt)
#pragma unroll
        for (int kc = 0; kc < 8; ++kc)
            A[rt][kc] = *(const hfrag*)(zh + (size_t)(wr0 + rt * 16 + lr) * ZDIM + kc * 32 + lk * 8);

    const char* ehpb = (const char*)ehf + (size_t)cp * 8 * 32768;  // this cp half

    // prologue: stage segment 0 into buf0
    {
        const char* src = ehpb;
        uint4 s0 = *(const uint4*)(src + tid * 16);
        uint4 s1 = *(const uint4*)(src + 4096 + tid * 16);
        uint4 s2 = *(const uint4*)(src + 8192 + tid * 16);
        uint4 s3 = *(const uint4*)(src + 12288 + tid * 16);
        *(uint4*)(&ehL[0][tid * 16])         = s0;
        *(uint4*)(&ehL[0][4096 + tid * 16])  = s1;
        *(uint4*)(&ehL[0][8192 + tid * 16])  = s2;
        *(uint4*)(&ehL[0][12288 + tid * 16]) = s3;
    }
    __syncthreads();   // seg0 staged; also covers sse init

    ffrag acc[2][4];
    int bcnt[2][4];    // per-row emission count, carried across each c8 pair

#pragma unroll 1
    for (int cc = 0; cc < 8; ++cc) {
        const int c16 = cp * 8 + cc;
        const int c8  = c16 >> 1;

        // ===== phase h=0: compute seg 2cc (buf0, kc 0..3); stage 2cc+1 -> buf1
        {
#pragma unroll
            for (int rt = 0; rt < 2; ++rt)
#pragma unroll
                for (int ct = 0; ct < 4; ++ct) acc[rt][ct] = (ffrag)(0.0f);
            const char* src = ehpb + (size_t)(2 * cc + 1) * 16384;
            uint4 s0 = *(const uint4*)(src + tid * 16);
            uint4 s1 = *(const uint4*)(src + 4096 + tid * 16);
            uint4 s2 = *(const uint4*)(src + 8192 + tid * 16);
            uint4 s3 = *(const uint4*)(src + 12288 + tid * 16);
            const char* buf = ehL[0];
#pragma unroll
            for (int kcl = 0; kcl < 4; ++kcl) {
#pragma unroll
                for (int ct = 0; ct < 4; ++ct) {
                    hfrag bh = *(const hfrag*)(buf + (size_t)(kcl * 4 + ct) * 1024 + (size_t)lane * 16);
                    acc[0][ct] = __builtin_amdgcn_mfma_f32_16x16x32_f16(A[0][kcl], bh, acc[0][ct], 0, 0, 0);
                    acc[1][ct] = __builtin_amdgcn_mfma_f32_16x16x32_f16(A[1][kcl], bh, acc[1][ct], 0, 0, 0);
                }
            }
            char* dst = ehL[1];
            *(uint4*)(dst + tid * 16)         = s0;
            *(uint4*)(dst + 4096 + tid * 16)  = s1;
            *(uint4*)(dst + 8192 + tid * 16)  = s2;
            *(uint4*)(dst + 12288 + tid * 16) = s3;
            __syncthreads();
        }

        // ===== phase h=1: compute seg 2cc+1 (buf1, kc 4..7); stage 2cc+2 -> buf0
        {
            uint4 s0, s1, s2, s3;
            const bool more = (cc < 7);
            if (more) {
                const char* src = ehpb + (size_t)(2 * cc + 2) * 16384;
                s0 = *(const uint4*)(src + tid * 16);
                s1 = *(const uint4*)(src + 4096 + tid * 16);
                s2 = *(const uint4*)(src + 8192 + tid * 16);
                s3 = *(const uint4*)(src + 12288 + tid * 16);
            }
            const char* buf = ehL[1];
#pragma unroll
            for (int kcl = 0; kcl < 4; ++kcl) {
#pragma unroll
                for (int ct = 0; ct < 4; ++ct) {
                    hfrag bh = *(const hfrag*)(buf + (size_t)(kcl * 4 + ct) * 1024 + (size_t)lane * 16);
                    acc[0][ct] = __builtin_amdgcn_mfma_f32_16x16x32_f16(A[0][4 + kcl], bh, acc[0][ct], 0, 0, 0);
                    acc[1][ct] = __builtin_amdgcn_mfma_f32_16x16x32_f16(A[1][4 + kcl], bh, acc[1][ct], 0, 0, 0);
                }
            }
            if (more) {
                char* dst = ehL[0];
                *(uint4*)(dst + tid * 16)         = s0;
                *(uint4*)(dst + 4096 + tid * 16)  = s1;
                *(uint4*)(dst + 8192 + tid * 16)  = s2;
                *(uint4*)(dst + 12288 + tid * 16) = s3;
            }

            // ---- epilogue for c16: d~ = fl(fl(sz+se) - acc/32) ----
            float rmin[2][4];
#pragma unroll
            for (int rt = 0; rt < 2; ++rt)
#pragma unroll
                for (int j = 0; j < 4; ++j) rmin[rt][j] = __builtin_inff();
#pragma unroll
            for (int rt = 0; rt < 2; ++rt)
#pragma unroll
                for (int ct = 0; ct < 4; ++ct) {
                    float sec = sse[c16 * 64 + ct * 16 + lr];
#pragma unroll
                    for (int j = 0; j < 4; ++j) {
                        float dd = __fsub_rn(__fadd_rn(szv[rt][j], sec), 0.03125f * acc[rt][ct][j]);
                        rmin[rt][j] = fminf(rmin[rt][j], dd);
                    }
                }
#pragma unroll
            for (int m = 1; m < 16; m <<= 1)
#pragma unroll
                for (int rt = 0; rt < 2; ++rt)
#pragma unroll
                    for (int j = 0; j < 4; ++j)
                        rmin[rt][j] = fminf(rmin[rt][j], __shfl_xor(rmin[rt][j], m, 64));
            if (lr == 0) {
#pragma unroll
                for (int rt = 0; rt < 2; ++rt)
#pragma unroll
                    for (int j = 0; j < 4; ++j)
                        cqmin[(size_t)(wr0 + rt * 16 + lk * 4 + j) * NC16 + c16] = rmin[rt][j];
            }
            // ---- ballot-based emission (no atomics) ----
            if ((cc & 1) == 0) {
#pragma unroll
                for (int rt = 0; rt < 2; ++rt)
#pragma unroll
                    for (int j = 0; j < 4; ++j) bcnt[rt][j] = 0;
            }
#pragma unroll
            for (int rt = 0; rt < 2; ++rt)
#pragma unroll
                for (int j = 0; j < 4; ++j) {
                    const float thr = fmaf(2.0f, epsv[rt][j], rmin[rt][j]);
                    const int grow = wr0 + rt * 16 + lk * 4 + j;
#pragma unroll
                    for (int ct = 0; ct < 4; ++ct) {
                        float dd = __fsub_rn(__fadd_rn(szv[rt][j], sse[c16 * 64 + ct * 16 + lr]),
                                             0.03125f * acc[rt][ct][j]);
                        const bool emit = (dd <= thr);
                        u64 bal = __ballot(emit);
                        u32 grp = (u32)(bal >> (lk * 16)) & 0xFFFFu;
                        if (emit) {
                            int slot = bcnt[rt][j] + __popc(grp & ((1u << lr) - 1u));
                            if (slot < SLOTS) {
                                size_t base = ((size_t)grow * NC8 + c8) * SLOTS + slot;
                                cand_i[base] = c16 * 64 + ct * 16 + lr;
                                cand_d[base] = dd;
                            }
                        }
                        bcnt[rt][j] += __popc(grp);
                    }
                }
            if (cc & 1) {
                if (lr == 0) {
#pragma unroll
                    for (int rt = 0; rt < 2; ++rt)
#pragma unroll
                        for (int j = 0; j < 4; ++j)
                            cnt[(size_t)(wr0 + rt * 16 + lk * 4 + j) * NC8 + c8] = bcnt[rt][j];
                }
            }
            __syncthreads();
        }
    }
}

// ---------------- rescore stage 1: filter + fastpath + two worklists --------
// Also initializes rkey for slow rows (replaces the 512KB memset launch).
__global__ __launch_bounds__(256) void rescore_fast_kernel(
    const float* __restrict__ epsr, const float* __restrict__ cqmin,
    const int* __restrict__ cnt, const float* __restrict__ cand_d,
    const int* __restrict__ cand_i, int* __restrict__ out_idx,
    float* __restrict__ out_idx_f, int* __restrict__ wl, int* __restrict__ wl_cnt,
    int* __restrict__ wl2, int* __restrict__ wl2_cnt,
    int* __restrict__ np, int* __restrict__ pc, u64* __restrict__ rkey) {
    const int row = blockIdx.x * 256 + threadIdx.x;
    const int lane = threadIdx.x & 63;
    float cq[NC16];
#pragma unroll
    for (int i = 0; i < 4; ++i)
        *(float4*)&cq[i * 4] = *(const float4*)(cqmin + (size_t)row * NC16 + i * 4);
    float gmin = __builtin_inff();
#pragma unroll
    for (int i = 0; i < NC16; ++i) gmin = fminf(gmin, cq[i]);
    const float thr = fmaf(2.0f, epsr[row], gmin);

    int nc = 0, first_c = 0;
    bool scan = false;
#pragma unroll
    for (int c8 = 0; c8 < NC8; ++c8) {
        if (fminf(cq[2 * c8], cq[2 * c8 + 1]) > thr) continue;
        int n = cnt[(size_t)row * NC8 + c8];
        if (n > SLOTS) { scan = true; }
        else {
            for (int s = 0; s < n; ++s) {
                size_t base = ((size_t)row * NC8 + c8) * SLOTS + s;
                if (cand_d[base] <= thr) {
                    int c = cand_i[base];
                    if (nc == 0) first_c = c;
                    if (nc < MAXP) pc[(size_t)row * MAXP + nc] = c;
                    ++nc;
                }
            }
        }
    }
    if (nc > MAXP) scan = true;
    const bool fast = !scan && nc == 1;
    const bool pair = !scan && nc != 1;
    if (fast) {
        out_idx[row] = first_c;
        out_idx_f[row] = (float)first_c;
    } else {
        rkey[row] = ~0ull;            // init for the atomicMin merge
        if (pair) np[row] = nc;
    }
    {
        u64 mask = __ballot(pair);
        int cw = __popcll(mask);
        int base = 0;
        if (lane == 0 && cw) base = atomicAdd(wl_cnt, cw);
        base = __shfl(base, 0, 64);
        if (pair) {
            int rank = __popcll(mask & ((1ull << lane) - 1ull));
            wl[base + rank] = row;
        }
    }
    {
        u64 mask = __ballot(scan);
        int cw = __popcll(mask);
        int base = 0;
        if (lane == 0 && cw) base = atomicAdd(wl2_cnt, cw);
        base = __shfl(base, 0, 64);
        if (scan) {
            int rank = __popcll(mask & ((1ull << lane) - 1ull));
            wl2[base + rank] = row;
        }
    }
}

// ---------------- rescore stage 2 (merged): pair dots + chunk scans ---------
__global__ __launch_bounds__(256) void rescore_slow_kernel(
    const float* __restrict__ z, const float* __restrict__ e,
    const float* __restrict__ sz, const float* __restrict__ se,
    const float* __restrict__ epsr, const float* __restrict__ cqmin,
    const int* __restrict__ np, const int* __restrict__ pc,
    const int* __restrict__ wl, const int* __restrict__ wl_cnt,
    const int* __restrict__ wl2, const int* __restrict__ wl2_cnt,
    u64* __restrict__ rkey) {
    const int t0 = blockIdx.x * 256 + threadIdx.x;
    const int stride = gridDim.x * 256;
    // pair rows: thread per (row, candidate)
    const int total1 = wl_cnt[0] * MAXP;
    for (int t = t0; t < total1; t += stride) {
        const int wi = t >> 4, j = t & 15;
        const int row = wl[wi];
        if (j >= np[row]) continue;
        int c = pc[(size_t)row * MAXP + j];
        float m = exact_dot(z + (size_t)row * ZDIM, e + (size_t)c * ZDIM);
        float d = __fsub_rn(__fadd_rn(sz[row], se[c]), 2.0f * m);
        atomicMin(&rkey[row], ((u64)mono32(d) << 32) | (u32)c);
    }
    // scan rows: thread per (row, code), qualifying c8s only
    const int total2 = wl2_cnt[0] * KCODES;
    for (int t = t0; t < total2; t += stride) {
        const int si = t >> 10, c = t & 1023;
        const int row = wl2[si];
        float gmin = __builtin_inff();
#pragma unroll
        for (int i = 0; i < NC16; ++i)
            gmin = fminf(gmin, cqmin[(size_t)row * NC16 + i]);
        const float thr = fmaf(2.0f, epsr[row], gmin);
        const int c8 = c >> 7;
        if (fminf(cqmin[(size_t)row * NC16 + 2 * c8],
                  cqmin[(size_t)row * NC16 + 2 * c8 + 1]) > thr) continue;
        float m = exact_dot(z + (size_t)row * ZDIM, e + (size_t)c * ZDIM);
        float d = __fsub_rn(__fadd_rn(sz[row], se[c]), 2.0f * m);
        atomicMin(&rkey[row], ((u64)mono32(d) << 32) | (u32)c);
    }
}

// ---------------- rescore stage 3: unpack winners (both lists) --------------
__global__ __launch_bounds__(256) void rescore_final_kernel(
    const int* __restrict__ wl, const int* __restrict__ wl_cnt,
    const int* __restrict__ wl2, const int* __restrict__ wl2_cnt,
    const u64* __restrict__ rkey, int* __restrict__ out_idx,
    float* __restrict__ out_idx_f) {
    const int i = blockIdx.x * 256 + threadIdx.x;
    const int n1 = wl_cnt[0], n2 = wl2_cnt[0];
    if (i < n1 + n2) {
        const int row = (i < n1) ? wl[i] : wl2[i - n1];
        const int c = (int)(u32)rkey[row];
        out_idx[row] = c;
        out_idx_f[row] = (float)c;
    }
}

// ---------------- z_q_st + loss partial (no atomics) ----------------
__global__ __launch_bounds__(256) void zq_loss_kernel(
    const float* __restrict__ z, const float* __restrict__ e,
    const int* __restrict__ idx, float* __restrict__ out,
    double* __restrict__ partial) {
    const int tid = threadIdx.x;
    const int rl  = tid >> 6;
    const int ln  = tid & 63;
    const int row0 = blockIdx.x * 32;

    float acc = 0.0f;
#pragma unroll
    for (int it = 0; it < 8; ++it) {
        int row = row0 + it * 4 + rl;
        int code = idx[row];
        const float4 vz = *(const float4*)(z + (size_t)row  * ZDIM + ln * 4);
        const float4 vq = *(const float4*)(e + (size_t)code * ZDIM + ln * 4);
        float4 o;
        float dx = __fsub_rn(vq.x, vz.x);
        float dy = __fsub_rn(vq.y, vz.y);
        float dz_ = __fsub_rn(vq.z, vz.z);
        float dw = __fsub_rn(vq.w, vz.w);
        o.x = __fadd_rn(vz.x, dx);
        o.y = __fadd_rn(vz.y, dy);
        o.z = __fadd_rn(vz.z, dz_);
        o.w = __fadd_rn(vz.w, dw);
        *(float4*)(out + (size_t)row * ZDIM + ln * 4) = o;
        acc = __fadd_rn(acc, __fmul_rn(dx, dx));
        acc = __fadd_rn(acc, __fmul_rn(dy, dy));
        acc = __fadd_rn(acc, __fmul_rn(dz_, dz_));
        acc = __fadd_rn(acc, __fmul_rn(dw, dw));
    }

    __shared__ double red[256];
    red[tid] = (double)acc;
    __syncthreads();
#pragma unroll
    for (int s = 128; s > 0; s >>= 1) {
        if (tid < s) red[tid] += red[tid + s];
        __syncthreads();
    }
    if (tid == 0) partial[blockIdx.x] = red[0];
}

__global__ __launch_bounds__(256) void loss_final_kernel(
    const double* __restrict__ partial, float* __restrict__ out_loss) {
    const int tid = threadIdx.x;
    double s = 0.0;
    for (int i = tid; i < ZQ_BLOCKS; i += 256) s += partial[i];
    __shared__ double red[256];
    red[tid] = s;
    __syncthreads();
#pragma unroll
    for (int st = 128; st > 0; st >>= 1) {
        if (tid < st) red[tid] += red[tid + st];
        __syncthreads();
    }
    if (tid == 0) {
        double M = red[0] / 16777216.0;
        float m32 = (float)M;
        out_loss[0] = __fadd_rn(m32, __fmul_rn(0.25f, m32));
    }
}

extern "C" void kernel_launch(void* const* d_in, const int* in_sizes, int n_in,
                              void* d_out, int out_size, void* d_ws, size_t ws_size,
                              hipStream_t stream) {
    const float* z = (const float*)d_in[0];
    const float* e = (const float*)d_in[1];
    float* out = (float*)d_out;
    char* ws = (char*)d_ws;

    size_t off = 0;
    double* partial = (double*)(ws + off); off += ZQ_BLOCKS * sizeof(double);        // 16 KB
    float*  sz      = (float*) (ws + off); off += (size_t)N_ROWS * 4;                // 256 KB
    float*  epsr    = (float*) (ws + off); off += (size_t)N_ROWS * 4;                // 256 KB
    float*  se      = (float*) (ws + off); off += (size_t)KCODES * 4;                // 4 KB
    int*    idx     = (int*)   (ws + off); off += (size_t)N_ROWS * 4;                // 256 KB
    u16*    ehf     = (u16*)   (ws + off); off += (size_t)KCODES * ZDIM * 2;         // 512 KB
    float*  cqmin   = (float*) (ws + off); off += (size_t)N_ROWS * NC16 * 4;         // 4 MB
    int*    cnt     = (int*)   (ws + off); off += (size_t)N_ROWS * NC8 * 4;          // 2 MB
    float*  cand_d  = (float*) (ws + off); off += (size_t)N_ROWS * NC8 * SLOTS * 4;  // 8 MB
    int*    cand_i  = (int*)   (ws + off); off += (size_t)N_ROWS * NC8 * SLOTS * 4;  // 8 MB
    int*    wl      = (int*)   (ws + off); off += (size_t)N_ROWS * 4;                // 256 KB
    int*    wl2     = (int*)   (ws + off); off += (size_t)N_ROWS * 4;                // 256 KB
    int*    np      = (int*)   (ws + off); off += (size_t)N_ROWS * 4;                // 256 KB
    int*    pc      = (int*)   (ws + off); off += (size_t)N_ROWS * MAXP * 4;         // 4 MB
    u64*    rkey    = (u64*)   (ws + off); off += (size_t)N_ROWS * 8;                // 512 KB
    int*    wl_cnt  = (int*)   (ws + off); off += 16;
    int*    wl2_cnt = (int*)   (ws + off); off += 16;

    u16* zh = (u16*)out;   // fp16 z in d_out z_q region; zq_loss overwrites later

    hipMemsetAsync(wl_cnt, 0, 32, stream);
    prep_z_kernel<<<N_ROWS / 32, 256, 0, stream>>>(z, zh, sz, epsr);
    split_e_kernel<<<256, 256, 0, stream>>>(e, ehf);
    rowsq_kernel<<<KCODES / 256, 256, 0, stream>>>(e, se, KCODES);
    mfma_argmin_kernel<<<1024, 256, 0, stream>>>(zh, ehf, sz, se, epsr, cqmin, cnt, cand_d, cand_i);
    rescore_fast_kernel<<<N_ROWS / 256, 256, 0, stream>>>(epsr, cqmin, cnt, cand_d, cand_i,
                                                          idx, out + IDX_OFF, wl, wl_cnt,
                                                          wl2, wl2_cnt, np, pc, rkey);
    rescore_slow_kernel<<<1024, 256, 0, stream>>>(z, e, sz, se, epsr, cqmin, np, pc,
                                                  wl, wl_cnt, wl2, wl2_cnt, rkey);
    rescore_final_kernel<<<N_ROWS / 256, 256, 0, stream>>>(wl, wl_cnt, wl2, wl2_cnt, rkey,
                                                           idx, out + IDX_OFF);
    zq_loss_kernel<<<ZQ_BLOCKS, 256, 0, stream>>>(z, e, idx, out, partial);
    loss_final_kernel<<<1, 256, 0, stream>>>(partial, out + LOSS_OFF);
}